// Round 16
// baseline (188.601 us; speedup 1.0000x reference)
//
#include <hip/hip_runtime.h>
#include <math.h>

#define NL   4
#define H    256
#define NST  64
#define CIN  64
#define COUT 8
#define BB   8
#define LL   1024
#define NFFT 2048

typedef __attribute__((ext_vector_type(8))) short bf16x8;
typedef __attribute__((ext_vector_type(4))) short short4v;
typedef __attribute__((ext_vector_type(4))) int   int4v;
typedef __attribute__((ext_vector_type(4))) float f32x4;

__device__ __forceinline__ short f2bf(float f) {
  union { float f; unsigned u; } v; v.f = f;
  unsigned r = (v.u + 0x7fffu + ((v.u >> 16) & 1u)) >> 16;
  return (short)r;
}
__device__ __forceinline__ float b2f(short s) {
  union { unsigned u; float f; } v;
  v.u = ((unsigned)(unsigned short)s) << 16;
  return v.f;
}
__device__ __forceinline__ int IDX2(int a) { return a + (a >> 4); }
#define FBUF 2176   // 2048 + 128 pad

__device__ __forceinline__ float2 cadd(float2 a, float2 b) { return make_float2(a.x + b.x, a.y + b.y); }
__device__ __forceinline__ float2 csub(float2 a, float2 b) { return make_float2(a.x - b.x, a.y - b.y); }

// ---------------------------------------------------------------------------
// 2048-pt FFT pieces (Stockham radix-8 x3 + final radix-4), float2 LDS.
// ---------------------------------------------------------------------------
template <int SGN>
__device__ __forceinline__ void bfly8(const float2 a[8], float2 A[8]) {
  const float RH = 0.70710678118654752f;
  float2 s0 = cadd(a[0], a[4]), s1 = csub(a[0], a[4]);
  float2 s2 = cadd(a[2], a[6]), s3 = csub(a[2], a[6]);
  float2 mi = (SGN < 0) ? make_float2(s3.y, -s3.x) : make_float2(-s3.y, s3.x);
  float2 E0 = cadd(s0, s2), E1 = cadd(s1, mi), E2 = csub(s0, s2), E3 = csub(s1, mi);
  float2 t0 = cadd(a[1], a[5]), t1 = csub(a[1], a[5]);
  float2 t2 = cadd(a[3], a[7]), t3 = csub(a[3], a[7]);
  float2 mj = (SGN < 0) ? make_float2(t3.y, -t3.x) : make_float2(-t3.y, t3.x);
  float2 O0 = cadd(t0, t2), O1 = cadd(t1, mj), O2 = csub(t0, t2), O3 = csub(t1, mj);
  float2 W0 = O0;
  float2 W1 = (SGN < 0) ? make_float2((O1.x + O1.y) * RH, (O1.y - O1.x) * RH)
                        : make_float2((O1.x - O1.y) * RH, (O1.x + O1.y) * RH);
  float2 W2 = (SGN < 0) ? make_float2(O2.y, -O2.x) : make_float2(-O2.y, O2.x);
  float2 W3 = (SGN < 0) ? make_float2((O3.y - O3.x) * RH, -(O3.x + O3.y) * RH)
                        : make_float2(-(O3.x + O3.y) * RH, (O3.x - O3.y) * RH);
  A[0] = cadd(E0, W0); A[4] = csub(E0, W0);
  A[1] = cadd(E1, W1); A[5] = csub(E1, W1);
  A[2] = cadd(E2, W2); A[6] = csub(E2, W2);
  A[3] = cadd(E3, W3); A[7] = csub(E3, W3);
}

// stage 0 via tw pointer (kernelfft path)
template <int SGN>
__device__ __forceinline__ void fft_stage0_reg(const float2 a[8], float2* d,
                                               const float2* __restrict__ tw, int tid) {
  float2 A[8];
  bfly8<SGN>(a, A);
  const int base = 8 * tid;
  d[IDX2(base)] = A[0];
#pragma unroll
  for (int dd = 1; dd < 8; ++dd) {
    float2 w = tw[dd * tid];
    float wi = (SGN < 0) ? w.y : -w.y;
    d[IDX2(base + dd)] = make_float2(A[dd].x * w.x - A[dd].y * wi,
                                     A[dd].x * wi + A[dd].y * w.x);
  }
}

// stage 0 via preloaded per-thread twiddles w[dd-1] = tw[dd*tid] (conv path).
template <int SGN>
__device__ __forceinline__ void fft_stage0_reg_tw(const float2 a[8], float2* d,
                                                  const float2 w[7], int tid) {
  float2 A[8];
  bfly8<SGN>(a, A);
  const int base = 8 * tid;
  d[IDX2(base)] = A[0];
#pragma unroll
  for (int dd = 1; dd < 8; ++dd) {
    float wr = w[dd - 1].x;
    float wi = (SGN < 0) ? w[dd - 1].y : -w[dd - 1].y;
    d[IDX2(base + dd)] = make_float2(A[dd].x * wr - A[dd].y * wi,
                                     A[dd].x * wi + A[dd].y * wr);
  }
}

// stages m=8 (bA->bB) and m=64 (bB->bA); barrier before each stage's reads.
template <int SGN>
__device__ __forceinline__ void fft_mid_stages(float2* bA, float2* bB,
                                               const float2* __restrict__ tw, int tid) {
#pragma unroll
  for (int st = 1; st < 3; ++st) {
    float2* s = (st == 1) ? bA : bB;
    float2* d = (st == 1) ? bB : bA;
    const int m = 1 << (3 * st);
    __syncthreads();
    const int k  = tid & (m - 1);
    const int jm = tid - k;
    float2 a[8], A[8];
#pragma unroll
    for (int q = 0; q < 8; ++q) a[q] = s[IDX2(tid + 256 * q)];
    bfly8<SGN>(a, A);
    const int base = 8 * jm + k;
    d[IDX2(base)] = A[0];
#pragma unroll
    for (int dd = 1; dd < 8; ++dd) {
      float2 w = tw[dd * jm];
      float wi = (SGN < 0) ? w.y : -w.y;
      d[IDX2(base + dd * m)] = make_float2(A[dd].x * w.x - A[dd].y * wi,
                                           A[dd].x * wi + A[dd].y * w.x);
    }
  }
}

template <int SGN>
__device__ __forceinline__ void fft_final_r4_lds(const float2* s, float2* d, int tid) {
  __syncthreads();
#pragma unroll
  for (int q = 0; q < 2; ++q) {
    const int t = tid + (q << 8);
    float2 x0 = s[IDX2(t)], x1 = s[IDX2(t + 512)];
    float2 x2 = s[IDX2(t + 1024)], x3 = s[IDX2(t + 1536)];
    float2 s0 = cadd(x0, x2), s1 = csub(x0, x2);
    float2 s2 = cadd(x1, x3), s3 = csub(x1, x3);
    float2 mi = (SGN < 0) ? make_float2(s3.y, -s3.x) : make_float2(-s3.y, s3.x);
    d[IDX2(t)]        = cadd(s0, s2);
    d[IDX2(t + 512)]  = cadd(s1, mi);
    d[IDX2(t + 1024)] = csub(s0, s2);
    d[IDX2(t + 1536)] = csub(s1, mi);
  }
  __syncthreads();
}

// final radix-4 to registers: out0 = X[tid + {0,512,1024,1536}],
// out1 = X[tid+256 + {0,512,1024,1536}].
template <int SGN>
__device__ __forceinline__ void fft_final_r4_reg(const float2* s, int tid,
                                                 float2 out0[4], float2 out1[4]) {
  __syncthreads();
#pragma unroll
  for (int q = 0; q < 2; ++q) {
    const int t = tid + (q << 8);
    float2 x0 = s[IDX2(t)], x1 = s[IDX2(t + 512)];
    float2 x2 = s[IDX2(t + 1024)], x3 = s[IDX2(t + 1536)];
    float2 s0 = cadd(x0, x2), s1 = csub(x0, x2);
    float2 s2 = cadd(x1, x3), s3 = csub(x1, x3);
    float2 mi = (SGN < 0) ? make_float2(s3.y, -s3.x) : make_float2(-s3.y, s3.x);
    float2* o = q ? out1 : out0;
    o[0] = cadd(s0, s2);
    o[1] = cadd(s1, mi);
    o[2] = csub(s0, s2);
    o[3] = csub(s1, mi);
  }
}

// setup: twiddles, Win transpose, state projection, weight shuffle into MFMA
// fragment order:
// W1s chunk c: c = cblk*2048 + s*256 + n*64 + lane (cblk<8, s<8, n<4)
// W2s chunk c: c = cblk*2048 + s*128 + n*64 + lane (cblk<8, s<16, n<2)
__global__ __launch_bounds__(256) void k_setup(
    const float* __restrict__ W1, const float* __restrict__ W2, const float* __restrict__ Win,
    const float* __restrict__ init, const float* __restrict__ Wst,
    const float* __restrict__ bst, const float* __restrict__ bin,
    short* __restrict__ W1s, short* __restrict__ W2s, float* __restrict__ WinT,
    float* __restrict__ sp, float2* __restrict__ tw) {
  int idx = blockIdx.x * 256 + threadIdx.x;
  if (idx < 2048) {
    float s, c;
    sincosf(3.14159265358979323846f * (float)idx / 1024.0f, &s, &c);
    tw[idx] = make_float2(c, -s);
  }
  if (idx < 65536) {
    int i = idx >> 14, c = idx & 16383;
    int cblk = c >> 11, s = (c >> 8) & 7, n = (c >> 6) & 3, lane = c & 63;
    int cl = lane & 15, rg = lane >> 4;
    int col = cblk * 64 + n * 16 + cl;
    const float* srcp = W1 + ((size_t)(i * 512 + col)) * 256 + s * 32 + rg * 8;
    short* dstp = W1s + ((size_t)idx) * 8;
#pragma unroll
    for (int j = 0; j < 8; ++j) dstp[j] = f2bf(srcp[j]);
  } else if (idx < 131072) {
    int t = idx - 65536;
    int i = t >> 14, c = t & 16383;
    int cblk = c >> 11, s = (c >> 7) & 15, n = (c >> 6) & 1, lane = c & 63;
    int cl = lane & 15, rg = lane >> 4;
    int col = cblk * 32 + n * 16 + cl;
    const float* srcp = W2 + ((size_t)(i * 256 + col)) * 512 + s * 32 + rg * 8;
    short* dstp = W2s + ((size_t)t) * 8;
#pragma unroll
    for (int j = 0; j < 8; ++j) dstp[j] = f2bf(srcp[j]);
  }
  if (idx < 256 * 64) {
    int hh = idx / 64, c = idx % 64;
    WinT[c * 256 + hh] = Win[idx];
  }
  if (idx < BB * H) {
    int b = idx >> 8, h = idx & 255;
    float acc = bin[h] + bst[h];
#pragma unroll
    for (int c = 0; c < COUT; ++c) acc += init[b * COUT + c] * Wst[h * COUT + c];
    sp[idx] = acc;
  }
}

// Fused input-proj + LN1(layer0): 16 l-rows per block. xT (transposed bf16,
// [b][h][l], same layout as yT) + xnT (f32) written via the LDS tile.
__global__ __launch_bounds__(256) void k_in_ln1(
    const float* __restrict__ stim, const float* __restrict__ WinT,
    const float* __restrict__ sp, const float* __restrict__ lw, const float* __restrict__ lb,
    short* __restrict__ xT, float* __restrict__ xnT) {
  int blk = blockIdx.x;               // b*64 + ltile
  int b_ = blk >> 6, l0 = (blk & 63) << 4;
  int tid = threadIdx.x, wv = tid >> 6, lane = tid & 63;
  __shared__ float sc[16][CIN];
  __shared__ float T[16][256];
#pragma unroll
  for (int it = 0; it < 4; ++it) {
    int idx = tid + (it << 8);
    int r = idx & 15, c = idx >> 4;
    sc[r][c] = stim[(b_ * CIN + c) * LL + l0 + r];
  }
  __syncthreads();
  float4 sp4 = *(const float4*)&sp[b_ * H + lane * 4];
  float4 acc[4] = {sp4, sp4, sp4, sp4};
  for (int c = 0; c < CIN; ++c) {
    float4 wv4 = *(const float4*)&WinT[c * H + lane * 4];
#pragma unroll
    for (int rr = 0; rr < 4; ++rr) {
      float s = sc[wv * 4 + rr][c];
      acc[rr].x += s * wv4.x; acc[rr].y += s * wv4.y;
      acc[rr].z += s * wv4.z; acc[rr].w += s * wv4.w;
    }
  }
  // pass 1: pre-LN v -> T; transposed bf16 write of xT
#pragma unroll
  for (int rr = 0; rr < 4; ++rr)
    *(float4*)&T[wv * 4 + rr][lane * 4] = acc[rr];
  __syncthreads();
  {
    bf16x8 v0, v1;
#pragma unroll
    for (int l = 0; l < 8; ++l) v0[l] = f2bf(T[l][tid]);
#pragma unroll
    for (int l = 0; l < 8; ++l) v1[l] = f2bf(T[l + 8][tid]);
    short* dst = xT + ((size_t)(b_ * H + tid)) * LL + l0;
    *(bf16x8*)&dst[0] = v0;
    *(bf16x8*)&dst[8] = v1;
  }
  __syncthreads();
  // pass 2: LN -> T; transposed f32 write of xnT
  float4 w4 = *(const float4*)&lw[lane * 4];
  float4 c4 = *(const float4*)&lb[lane * 4];
#pragma unroll
  for (int rr = 0; rr < 4; ++rr) {
    int lr = wv * 4 + rr;
    float4 v = acc[rr];
    float s = v.x + v.y + v.z + v.w;
#pragma unroll
    for (int o = 32; o > 0; o >>= 1) s += __shfl_xor(s, o, 64);
    float m = s * (1.0f / H);
    float dx = v.x - m, dy = v.y - m, dz = v.z - m, dw = v.w - m;
    float q = dx * dx + dy * dy + dz * dz + dw * dw;
#pragma unroll
    for (int o = 32; o > 0; o >>= 1) q += __shfl_xor(q, o, 64);
    float rs = rsqrtf(q * (1.0f / H) + 1e-5f);
    float4 o4;
    o4.x = dx * rs * w4.x + c4.x; o4.y = dy * rs * w4.y + c4.y;
    o4.z = dz * rs * w4.z + c4.z; o4.w = dw * rs * w4.w + c4.w;
    *(float4*)&T[lr][lane * 4] = o4;
  }
  __syncthreads();
  float tmp[16];
#pragma unroll
  for (int l = 0; l < 16; ++l) tmp[l] = T[l][tid];
  float* dst = xnT + ((size_t)(b_ * H + tid)) * LL + l0;
#pragma unroll
  for (int l = 0; l < 16; l += 4) {
    float4 v = {tmp[l], tmp[l + 1], tmp[l + 2], tmp[l + 3]};
    *(float4*)&dst[l] = v;
  }
}

// All layers: blk = i*H + h. K[l] via 2-table lookup; FFT with register
// stage-0 and register final stage (kf written from registers).
__global__ __launch_bounds__(256) void k_kernelfft(
    const float* __restrict__ A_re, const float* __restrict__ A_im,
    const float* __restrict__ C_re, const float* __restrict__ C_im,
    const float* __restrict__ log_step, const float2* __restrict__ tw,
    float2* __restrict__ kf) {
  int blk = blockIdx.x;                 // i*H + h
  int i = blk >> 8;
  int tid = threadIdx.x;
  __shared__ float2 cb[NST], Mv[NST];
  __shared__ float2 bufA[FBUF], bufB[FBUF];
  float2* T1 = bufB;                    // [n][16], overlays FFT scratch
  float2* T2 = bufB + 1024;             // [n][16]
  float step = expf(log_step[blk]);
  int n = tid & 63, g = tid >> 6;
  float Ar = A_re[i * NST + n], Ai = A_im[i * NST + n];
  float dr = step * Ar, di = step * Ai;
  float er = expf(dr);
  float sn, cs; sincosf(di, &sn, &cs);
  float Er = er * cs, Ei = er * sn;     // E = exp(dA)
  if (g == 0) {
    float nr = Er - 1.0f, ni = Ei;
    float dnm = Ar * Ar + Ai * Ai;
    float qr = (nr * Ar + ni * Ai) / dnm;    // (exp(dA)-1)/A
    float qi = (ni * Ar - nr * Ai) / dnm;
    float Cr = C_re[(size_t)blk * NST + n], Ci = C_im[(size_t)blk * NST + n];
    cb[n] = make_float2(Cr * qr - Ci * qi, Cr * qi + Ci * qr);
    float pr = 1.f, pi = 0.f;
    T1[n * 16] = make_float2(1.f, 0.f);
    for (int a = 1; a < 16; ++a) {
      float t2 = pr * Er - pi * Ei; pi = pr * Ei + pi * Er; pr = t2;
      T1[n * 16 + a] = make_float2(pr, pi);
    }
  } else if (g == 1) {
    float xr = Er, xi = Ei;
#pragma unroll
    for (int j = 0; j < 4; ++j) { float t2 = xr * xr - xi * xi; xi = 2.f * xr * xi; xr = t2; }
    float pr = 1.f, pi = 0.f;
    T2[n * 16] = make_float2(1.f, 0.f);
    for (int a = 1; a < 16; ++a) {
      float t2 = pr * xr - pi * xi; pi = pr * xi + pi * xr; pr = t2;
      T2[n * 16 + a] = make_float2(pr, pi);
    }
    float mr2 = pr * xr - pi * xi, mi2 = pr * xi + pi * xr;   // E^256
    Mv[n] = make_float2(mr2, mi2);
  }
  __syncthreads();
  float kr[4] = {0.f, 0.f, 0.f, 0.f}, ki[4] = {0.f, 0.f, 0.f, 0.f};
  const int a_lo = tid & 15, a_hi = tid >> 4;
  for (int nn = 0; nn < NST; ++nn) {
    float2 t1 = T1[nn * 16 + a_lo];
    float2 t2v = T2[nn * 16 + a_hi];
    float pr = t1.x * t2v.x - t1.y * t2v.y;   // E^tid
    float pi = t1.x * t2v.y + t1.y * t2v.x;
    float2 c = cb[nn], m = Mv[nn];
#pragma unroll
    for (int q = 0; q < 4; ++q) {
      kr[q] += c.x * pr - c.y * pi;
      ki[q] += c.x * pi + c.y * pr;
      float t2 = pr * m.x - pi * m.y;         // p *= E^256
      pi = pr * m.y + pi * m.x;
      pr = t2;
    }
  }
  float2 a[8];
#pragma unroll
  for (int q = 0; q < 4; ++q) a[q] = make_float2(kr[q], ki[q]);
  a[4] = a[5] = a[6] = a[7] = make_float2(0.f, 0.f);
  fft_stage0_reg<-1>(a, bufA, tw, tid);
  fft_mid_stages<-1>(bufA, bufB, tw, tid);   // m=8: A->B, m=64: B->A
  float2 F0[4], F1[4];
  fft_final_r4_reg<-1>(bufA, tid, F0, F1);
  float2* kfh = kf + (size_t)blk * 1025;
  kfh[tid]       = F0[0];
  kfh[tid + 512] = F0[1];
  kfh[tid + 256] = F1[0];
  kfh[tid + 768] = F1[1];
  if (tid == 0) kfh[1024] = F0[2];
}

// Two rows packed per complex FFT; register stage-0 in, register final out.
// Spectral multiply FUSED into the inverse stage-0 gather (saves one LDS
// pass + barrier): each thread reads F[k] and F[2048-k] from the spectrum,
// applies the Hermitian/imag-drop product per position, feeds bfly8.
__global__ __launch_bounds__(256) void k_conv(
    const float* __restrict__ xnT, const float2* __restrict__ kf,
    const float* __restrict__ D, const float2* __restrict__ tw, short* __restrict__ yT) {
  int blk = blockIdx.x;                 // b*128 + hp
  int b_ = blk >> 7, hp = blk & 127;
  int h0 = hp * 2, h1 = h0 + 1;
  int r0 = b_ * H + h0;
  int tid = threadIdx.x;
  __shared__ float2 bufA[FBUF], bufB[FBUF];
  float2 w0[7];
#pragma unroll
  for (int dd = 1; dd < 8; ++dd) w0[dd - 1] = tw[dd * tid];
  float u0[4], u1[4];
  const float* x0 = xnT + (size_t)r0 * LL;
  const float* x1 = x0 + LL;
  float2 a[8];
#pragma unroll
  for (int q = 0; q < 4; ++q) {
    int l = tid + (q << 8);
    float v0 = x0[l], v1 = x1[l];
    u0[q] = v0; u1[q] = v1;
    a[q] = make_float2(v0, v1);
  }
  a[4] = a[5] = a[6] = a[7] = make_float2(0.f, 0.f);
  fft_stage0_reg_tw<-1>(a, bufA, w0, tid);
  fft_mid_stages<-1>(bufA, bufB, tw, tid);   // result of m=64 in bufA
  fft_final_r4_lds<-1>(bufA, bufB, tid);     // spectrum F in bufB (barrier after)
  const float2* kf0 = kf + (size_t)h0 * 1025;
  const float2* kf1 = kf + (size_t)h1 * 1025;
  // fused spectral multiply + inverse stage-0 gather
  float2 g[8];
#pragma unroll
  for (int q = 0; q < 8; ++q) {
    int k = tid + (q << 8);
    float2 Z;
    if (tid == 0 && q == 0) {
      float2 Fz = bufB[IDX2(0)];
      Z = make_float2(Fz.x * kf0[0].x, Fz.y * kf1[0].x);
    } else if (tid == 0 && q == 4) {
      float2 Fn = bufB[IDX2(1024)];
      Z = make_float2(Fn.x * kf0[1024].x, Fn.y * kf1[1024].x);
    } else {
      int km = (k < 1024) ? k : 2048 - k;
      float2 Flo = bufB[IDX2(km)];
      float2 Fhi = bufB[IDX2(2048 - km)];
      float u0r = 0.5f * (Flo.x + Fhi.x), u0i = 0.5f * (Flo.y - Fhi.y);   // U0[km]
      float dr_ = 0.5f * (Flo.x - Fhi.x), di_ = 0.5f * (Flo.y + Fhi.y);
      float u1r = di_, u1i = -dr_;                                        // U1[km]
      float2 k0 = kf0[km], k1 = kf1[km];
      float z0r = u0r * k0.x - u0i * k0.y, z0i = u0r * k0.y + u0i * k0.x;
      float z1r = u1r * k1.x - u1i * k1.y, z1i = u1r * k1.y + u1i * k1.x;
      Z = (k < 1024) ? make_float2(z0r - z1i, z0i + z1r)
                     : make_float2(z0r + z1i, z1r - z0i);
    }
    g[q] = Z;
  }
  fft_stage0_reg_tw<1>(g, bufA, w0, tid);    // writes bufA (reads of bufA done)
  fft_mid_stages<1>(bufA, bufB, tw, tid);    // m=8: A->B, m=64: B->A
  float2 z0[4], z1[4];
  fft_final_r4_reg<1>(bufA, tid, z0, z1);
  float Dh0 = D[h0], Dh1 = D[h1];
  short* y0 = yT + (size_t)r0 * LL;
  short* y1 = y0 + LL;
  const float s = 1.0f / NFFT;
  y0[tid]       = f2bf(z0[0].x * s + Dh0 * u0[0]);
  y0[tid + 256] = f2bf(z1[0].x * s + Dh0 * u0[1]);
  y0[tid + 512] = f2bf(z0[1].x * s + Dh0 * u0[2]);
  y0[tid + 768] = f2bf(z1[1].x * s + Dh0 * u0[3]);
  y1[tid]       = f2bf(z0[0].y * s + Dh1 * u1[0]);
  y1[tid + 256] = f2bf(z1[0].y * s + Dh1 * u1[1]);
  y1[tid + 512] = f2bf(z0[1].y * s + Dh1 * u1[2]);
  y1[tid + 768] = f2bf(z1[1].y * s + Dh1 * u1[3]);
}

// ---------------------------------------------------------------------------
// Mega MLP kernel, 512 threads, 16-row tile, grid 512 -> 2 blocks/CU.
// xT, yT both bf16 transposed [b][h][l]: Phase A = 4x8B loads, Phase D =
// 2x8B stores (was 8x scalar each). GEMM1 s=0,1 prefetched before Phase A;
// GEMM2 s=0,1 prefetched before the GELU epilogue; setprio around MFMA.
// LDS: A1[16][264]s @0 | A2[16][520]s @8448 | red @25088
//      LAST: Txn[16][260]f @0, wlds[8][258]f @16896
// ---------------------------------------------------------------------------
#define TXS 260
template <bool LAST>
__global__ __launch_bounds__(512, 4) void k_mlp(
    const short* __restrict__ W1p, const float* __restrict__ b1p,
    const short* __restrict__ W2p, const float* __restrict__ b2p,
    short* __restrict__ xT, const short* __restrict__ yT,
    const float* __restrict__ ln2w, const float* __restrict__ ln2b,
    const float* __restrict__ ln1w, const float* __restrict__ ln1b,
    float* __restrict__ xnT,
    const float* __restrict__ Wout, const float* __restrict__ bout,
    float* __restrict__ out) {
  const int m0 = blockIdx.x * 16;
  const int b_ = m0 >> 10, l0 = m0 & 1023;
  const int tid = threadIdx.x;
  const int lane = tid & 63, wid = tid >> 6;       // 8 waves
  const int rg = lane >> 4, cl = lane & 15;
  __shared__ __attribute__((aligned(16))) char smem[26112];
  short* A1  = (short*)smem;                 // [16][264]
  short* A2  = (short*)(smem + 8448);        // [16][520]
  float* red = (float*)(smem + 25088);       // [8][16][2]
  float* Txn = (float*)smem;                 // [16][260] (LAST)
  float* wlds = (float*)(smem + 16896);      // [8][258]  (LAST)

  const short* w1base = W1p + (size_t)wid * 16384 + lane * 8;
  const short* w2base = W2p + (size_t)wid * 16384 + lane * 8;
  // prefetch GEMM1 s=0,1 fragments — hides L2 latency under Phase A
  bf16x8 pre[8];
#pragma unroll
  for (int n = 0; n < 8; ++n)
    pre[n] = *(const bf16x8*)(w1base + n * 512);

  // ---- Phase A: residual add (registers) + LN2 -> A1 bf16 ----
  float v[2][4];                             // [n][r], rows rg*4+r
  float wl2[2], bl2[2];
#pragma unroll
  for (int n = 0; n < 2; ++n) {
    int col = wid * 32 + n * 16 + cl;
    wl2[n] = ln2w[col]; bl2[n] = ln2b[col];
  }
  float sum[4], sq[4];
#pragma unroll
  for (int r = 0; r < 4; ++r) { sum[r] = 0.f; sq[r] = 0.f; }
#pragma unroll
  for (int n = 0; n < 2; ++n) {
    int col = wid * 32 + n * 16 + cl;
    size_t base = ((size_t)(b_ * H + col)) * LL + l0 + rg * 4;
    short4v y4 = *(const short4v*)&yT[base];
    short4v x4 = *(const short4v*)&xT[base];
#pragma unroll
    for (int r = 0; r < 4; ++r) {
      float val = b2f(x4[r]) + b2f(y4[r]);
      v[n][r] = val;
      sum[r] += val; sq[r] += val * val;
    }
  }
#pragma unroll
  for (int r = 0; r < 4; ++r) {
#pragma unroll
    for (int o = 1; o < 16; o <<= 1) {
      sum[r] += __shfl_xor(sum[r], o, 64);
      sq[r]  += __shfl_xor(sq[r], o, 64);
    }
  }
  if (cl == 0) {
#pragma unroll
    for (int r = 0; r < 4; ++r) {
      int row = rg * 4 + r;
      red[(wid * 16 + row) * 2]     = sum[r];
      red[(wid * 16 + row) * 2 + 1] = sq[r];
    }
  }
  __syncthreads();
#pragma unroll
  for (int r = 0; r < 4; ++r) {
    int row = rg * 4 + r;
    float S = 0.f, Q = 0.f;
#pragma unroll
    for (int w = 0; w < 8; ++w) { S += red[(w * 16 + row) * 2]; Q += red[(w * 16 + row) * 2 + 1]; }
    float mean = S * (1.0f / H);
    float var = Q * (1.0f / H) - mean * mean;
    float rs = rsqrtf(var + 1e-5f);
#pragma unroll
    for (int n = 0; n < 2; ++n) {
      int col = wid * 32 + n * 16 + cl;
      A1[row * 264 + col] = f2bf((v[n][r] - mean) * rs * wl2[n] + bl2[n]);
    }
  }
  __syncthreads();   // A1 complete; K-loops below are barrier-free

  // ---- Phase B: GEMM1 (16x512, K=256); wave w -> cols w*64..w*64+63 ----
  f32x4 acc1[4];
#pragma unroll
  for (int n = 0; n < 4; ++n) acc1[n] = (f32x4){0.f, 0.f, 0.f, 0.f};
  {
#pragma unroll
    for (int s = 0; s < 8; ++s) {
      const int kk = s * 32;
      bf16x8 af, bfv[4];
      if (s < 2) {
#pragma unroll
        for (int n = 0; n < 4; ++n) bfv[n] = pre[s * 4 + n];
      } else {
#pragma unroll
        for (int n = 0; n < 4; ++n)
          bfv[n] = *(const bf16x8*)(w1base + (s * 4 + n) * 512);
      }
      af = *(const bf16x8*)&A1[cl * 264 + kk + rg * 8];
      __builtin_amdgcn_s_setprio(1);
#pragma unroll
      for (int n = 0; n < 4; ++n)
        acc1[n] = __builtin_amdgcn_mfma_f32_16x16x32_bf16(af, bfv[n], acc1[n], 0, 0, 0);
      __builtin_amdgcn_s_setprio(0);
    }
  }
  // prefetch GEMM2 s=0,1 — hides W2 L2 latency under GELU epilogue + barrier
  bf16x8 pre2[4];
#pragma unroll
  for (int n = 0; n < 4; ++n)
    pre2[n] = *(const bf16x8*)(w2base + n * 512);
  // +b1, GELU -> A2 bf16
#pragma unroll
  for (int n = 0; n < 4; ++n) {
    int col = wid * 64 + n * 16 + cl;
    float bb = b1p[col];
#pragma unroll
    for (int r = 0; r < 4; ++r) {
      int row = rg * 4 + r;
      float g = acc1[n][r] + bb;
      g = 0.5f * g * (1.0f + erff(g * 0.70710678118654752f));
      A2[row * 520 + col] = f2bf(g);
    }
  }
  __syncthreads();   // A2 complete

  // ---- Phase C: GEMM2 (16x256, K=512); wave w -> cols w*32..w*32+31 ----
  f32x4 acc2[2];
#pragma unroll
  for (int n = 0; n < 2; ++n) acc2[n] = (f32x4){0.f, 0.f, 0.f, 0.f};
  {
#pragma unroll
    for (int s = 0; s < 16; ++s) {
      const int kk = s * 32;
      bf16x8 af, bfv[2];
      if (s < 2) {
#pragma unroll
        for (int n = 0; n < 2; ++n) bfv[n] = pre2[s * 2 + n];
      } else {
#pragma unroll
        for (int n = 0; n < 2; ++n)
          bfv[n] = *(const bf16x8*)(w2base + (s * 2 + n) * 512);
      }
      af = *(const bf16x8*)&A2[cl * 520 + kk + rg * 8];
      __builtin_amdgcn_s_setprio(1);
#pragma unroll
      for (int n = 0; n < 2; ++n)
        acc2[n] = __builtin_amdgcn_mfma_f32_16x16x32_bf16(af, bfv[n], acc2[n], 0, 0, 0);
      __builtin_amdgcn_s_setprio(0);
    }
  }

  // ---- Phase D: vf = acc2 + b2 + v; LN1-next + xnT | output proj ----
  float bv[2], wl1[2], bl1[2];
#pragma unroll
  for (int n = 0; n < 2; ++n) {
    int col = wid * 32 + n * 16 + cl;
    bv[n] = b2p[col];
    if (!LAST) { wl1[n] = ln1w[col]; bl1[n] = ln1b[col]; }
  }
#pragma unroll
  for (int r = 0; r < 4; ++r) { sum[r] = 0.f; sq[r] = 0.f; }
#pragma unroll
  for (int n = 0; n < 2; ++n) {
#pragma unroll
    for (int r = 0; r < 4; ++r) {
      float vf = acc2[n][r] + bv[n] + v[n][r];
      acc2[n][r] = vf;
      sum[r] += vf; sq[r] += vf * vf;
    }
  }

  if (LAST) {
    __syncthreads();   // all waves done reading A2 before Txn overlays it
#pragma unroll
    for (int n = 0; n < 2; ++n) {
      int col = wid * 32 + n * 16 + cl;
#pragma unroll
      for (int r = 0; r < 4; ++r) {
        int row = rg * 4 + r;
        Txn[row * TXS + col] = acc2[n][r];
      }
    }
#pragma unroll
    for (int it = 0; it < 4; ++it) {
      int idx = tid + (it << 9);
      wlds[(idx >> 8) * 258 + (idx & 255)] = Wout[idx];
    }
    __syncthreads();
    if (tid < 128) {
      int row = tid >> 3, co = tid & 7;
      float p = bout[co];
      const float* tr = Txn + row * TXS;
      const float* wr = wlds + co * 258;
#pragma unroll 4
      for (int c = 0; c < H; ++c) p += tr[c] * wr[c];
      out[((b_ * COUT + co) << 10) + l0 + row] = p;
    }
  } else {
#pragma unroll
    for (int r = 0; r < 4; ++r) {
#pragma unroll
      for (int o = 1; o < 16; o <<= 1) {
        sum[r] += __shfl_xor(sum[r], o, 64);
        sq[r]  += __shfl_xor(sq[r], o, 64);
      }
    }
    if (cl == 0) {
#pragma unroll
      for (int r = 0; r < 4; ++r) {
        int row = rg * 4 + r;
        red[(wid * 16 + row) * 2]     = sum[r];
        red[(wid * 16 + row) * 2 + 1] = sq[r];
      }
    }
    __syncthreads();   // red ready AND all waves done with A1/A2 (Txn safe)
    short4v xs[2];
#pragma unroll
    for (int r = 0; r < 4; ++r) {
      int row = rg * 4 + r;
      float S = 0.f, Q = 0.f;
#pragma unroll
      for (int w = 0; w < 8; ++w) { S += red[(w * 16 + row) * 2]; Q += red[(w * 16 + row) * 2 + 1]; }
      float mean = S * (1.0f / H);
      float var = Q * (1.0f / H) - mean * mean;
      float rs = rsqrtf(var + 1e-5f);
#pragma unroll
      for (int n = 0; n < 2; ++n) {
        int col = wid * 32 + n * 16 + cl;
        float vf = acc2[n][r];
        xs[n][r] = f2bf(vf);
        Txn[row * TXS + col] = (vf - mean) * rs * wl1[n] + bl1[n];
      }
    }
#pragma unroll
    for (int n = 0; n < 2; ++n) {
      int col = wid * 32 + n * 16 + cl;
      *(short4v*)&xT[((size_t)(b_ * H + col)) * LL + l0 + rg * 4] = xs[n];
    }
    __syncthreads();
    // transposed copy: 512 threads, each moves 8 l-contiguous floats
    int h = tid & 255, seg = (tid >> 8) * 8;
    float tmp[8];
#pragma unroll
    for (int l = 0; l < 8; ++l) tmp[l] = Txn[(seg + l) * TXS + h];
    float* dst = xnT + ((size_t)(b_ * H + h)) * LL + l0 + seg;
#pragma unroll
    for (int l = 0; l < 8; l += 4) {
      float4 v4 = {tmp[l], tmp[l + 1], tmp[l + 2], tmp[l + 3]};
      *(float4*)&dst[l] = v4;
    }
  }
}

extern "C" void kernel_launch(void* const* d_in, const int* in_sizes, int n_in,
                              void* d_out, int out_size, void* d_ws, size_t ws_size,
                              hipStream_t stream) {
  const float* stim  = (const float*)d_in[0];
  const float* init  = (const float*)d_in[1];
  const float* A_re  = (const float*)d_in[2];
  const float* A_im  = (const float*)d_in[3];
  const float* C_re  = (const float*)d_in[4];
  const float* C_im  = (const float*)d_in[5];
  const float* Dp    = (const float*)d_in[6];
  const float* lstep = (const float*)d_in[7];
  const float* ln1w  = (const float*)d_in[8];
  const float* ln1b  = (const float*)d_in[9];
  const float* ln2w  = (const float*)d_in[10];
  const float* ln2b  = (const float*)d_in[11];
  const float* W1    = (const float*)d_in[12];
  const float* b1    = (const float*)d_in[13];
  const float* W2    = (const float*)d_in[14];
  const float* b2    = (const float*)d_in[15];
  const float* Win   = (const float*)d_in[16];
  const float* bin   = (const float*)d_in[17];
  const float* Wst   = (const float*)d_in[18];
  const float* bst   = (const float*)d_in[19];
  const float* Wout  = (const float*)d_in[20];
  const float* bout  = (const float*)d_in[21];
  float* out = (float*)d_out;
  float* ws = (float*)d_ws;

  size_t o = 0;
  auto alloc = [&](size_t nfloats) { size_t r = o; o += (nfloats + 63) & ~(size_t)63; return r; };
  short*  xT   = (short*)(ws + alloc((size_t)BB * LL * H / 2));
  float*  xnT  = ws + alloc((size_t)BB * H * LL);
  short*  yT   = (short*)(ws + alloc((size_t)BB * H * LL / 2));
  float2* kf   = (float2*)(ws + alloc((size_t)NL * H * 1025 * 2));
  short*  W1s  = (short*)(ws + alloc((size_t)NL * 512 * 256 / 2));
  short*  W2s  = (short*)(ws + alloc((size_t)NL * 256 * 512 / 2));
  float*  WinT = ws + alloc((size_t)64 * 256);
  float*  sp   = ws + alloc((size_t)BB * H);
  float2* tw   = (float2*)(ws + alloc((size_t)2048 * 2));
  (void)ws_size; (void)in_sizes; (void)n_in; (void)out_size;

  k_setup<<<512, 256, 0, stream>>>(W1, W2, Win, init, Wst, bst, bin,
                                   W1s, W2s, WinT, sp, tw);
  k_kernelfft<<<NL * H, 256, 0, stream>>>(A_re, A_im, C_re, C_im, lstep, tw, kf);
  k_in_ln1<<<BB * 64, 256, 0, stream>>>(stim, WinT, sp, ln1w, ln1b, xT, xnT);

  for (int i = 0; i < NL; ++i) {
    k_conv<<<BB * H / 2, 256, 0, stream>>>(xnT, kf + (size_t)i * H * 1025,
                                           Dp + i * H, tw, yT);
    if (i < NL - 1) {
      k_mlp<false><<<512, 512, 0, stream>>>(
          W1s + (size_t)i * 512 * 256, b1 + i * 512,
          W2s + (size_t)i * 256 * 512, b2 + i * H,
          xT, yT, ln2w + i * H, ln2b + i * H,
          ln1w + (i + 1) * H, ln1b + (i + 1) * H, xnT,
          nullptr, nullptr, nullptr);
    } else {
      k_mlp<true><<<512, 512, 0, stream>>>(
          W1s + (size_t)i * 512 * 256, b1 + i * 512,
          W2s + (size_t)i * 256 * 512, b2 + i * H,
          xT, yT, ln2w + i * H, ln2b + i * H,
          nullptr, nullptr, nullptr,
          Wout, bout, out);
    }
  }
}

// Round 17
// 182.183 us; speedup vs baseline: 1.0352x; 1.0352x over previous
//
#include <hip/hip_runtime.h>
#include <math.h>

#define NL   4
#define H    256
#define NST  64
#define CIN  64
#define COUT 8
#define BB   8
#define LL   1024
#define NFFT 2048

typedef __attribute__((ext_vector_type(8))) short bf16x8;
typedef __attribute__((ext_vector_type(4))) short short4v;
typedef __attribute__((ext_vector_type(4))) int   int4v;
typedef __attribute__((ext_vector_type(4))) float f32x4;

__device__ __forceinline__ short f2bf(float f) {
  union { float f; unsigned u; } v; v.f = f;
  unsigned r = (v.u + 0x7fffu + ((v.u >> 16) & 1u)) >> 16;
  return (short)r;
}
__device__ __forceinline__ float b2f(short s) {
  union { unsigned u; float f; } v;
  v.u = ((unsigned)(unsigned short)s) << 16;
  return v.f;
}
__device__ __forceinline__ int IDX2(int a) { return a + (a >> 4); }
#define FBUF 2176   // 2048 + 128 pad

__device__ __forceinline__ float2 cadd(float2 a, float2 b) { return make_float2(a.x + b.x, a.y + b.y); }
__device__ __forceinline__ float2 csub(float2 a, float2 b) { return make_float2(a.x - b.x, a.y - b.y); }

// ---------------------------------------------------------------------------
// 2048-pt FFT pieces (Stockham radix-8 x3 + final radix-4), float2 LDS.
// ---------------------------------------------------------------------------
template <int SGN>
__device__ __forceinline__ void bfly8(const float2 a[8], float2 A[8]) {
  const float RH = 0.70710678118654752f;
  float2 s0 = cadd(a[0], a[4]), s1 = csub(a[0], a[4]);
  float2 s2 = cadd(a[2], a[6]), s3 = csub(a[2], a[6]);
  float2 mi = (SGN < 0) ? make_float2(s3.y, -s3.x) : make_float2(-s3.y, s3.x);
  float2 E0 = cadd(s0, s2), E1 = cadd(s1, mi), E2 = csub(s0, s2), E3 = csub(s1, mi);
  float2 t0 = cadd(a[1], a[5]), t1 = csub(a[1], a[5]);
  float2 t2 = cadd(a[3], a[7]), t3 = csub(a[3], a[7]);
  float2 mj = (SGN < 0) ? make_float2(t3.y, -t3.x) : make_float2(-t3.y, t3.x);
  float2 O0 = cadd(t0, t2), O1 = cadd(t1, mj), O2 = csub(t0, t2), O3 = csub(t1, mj);
  float2 W0 = O0;
  float2 W1 = (SGN < 0) ? make_float2((O1.x + O1.y) * RH, (O1.y - O1.x) * RH)
                        : make_float2((O1.x - O1.y) * RH, (O1.x + O1.y) * RH);
  float2 W2 = (SGN < 0) ? make_float2(O2.y, -O2.x) : make_float2(-O2.y, O2.x);
  float2 W3 = (SGN < 0) ? make_float2((O3.y - O3.x) * RH, -(O3.x + O3.y) * RH)
                        : make_float2(-(O3.x + O3.y) * RH, (O3.x - O3.y) * RH);
  A[0] = cadd(E0, W0); A[4] = csub(E0, W0);
  A[1] = cadd(E1, W1); A[5] = csub(E1, W1);
  A[2] = cadd(E2, W2); A[6] = csub(E2, W2);
  A[3] = cadd(E3, W3); A[7] = csub(E3, W3);
}

// stage 0 via tw pointer (kernelfft path)
template <int SGN>
__device__ __forceinline__ void fft_stage0_reg(const float2 a[8], float2* d,
                                               const float2* __restrict__ tw, int tid) {
  float2 A[8];
  bfly8<SGN>(a, A);
  const int base = 8 * tid;
  d[IDX2(base)] = A[0];
#pragma unroll
  for (int dd = 1; dd < 8; ++dd) {
    float2 w = tw[dd * tid];
    float wi = (SGN < 0) ? w.y : -w.y;
    d[IDX2(base + dd)] = make_float2(A[dd].x * w.x - A[dd].y * wi,
                                     A[dd].x * wi + A[dd].y * w.x);
  }
}

// stage 0 via preloaded per-thread twiddles w[dd-1] = tw[dd*tid] (conv path).
template <int SGN>
__device__ __forceinline__ void fft_stage0_reg_tw(const float2 a[8], float2* d,
                                                  const float2 w[7], int tid) {
  float2 A[8];
  bfly8<SGN>(a, A);
  const int base = 8 * tid;
  d[IDX2(base)] = A[0];
#pragma unroll
  for (int dd = 1; dd < 8; ++dd) {
    float wr = w[dd - 1].x;
    float wi = (SGN < 0) ? w[dd - 1].y : -w[dd - 1].y;
    d[IDX2(base + dd)] = make_float2(A[dd].x * wr - A[dd].y * wi,
                                     A[dd].x * wi + A[dd].y * wr);
  }
}

// stages m=8 (bA->bB) and m=64 (bB->bA); barrier before each stage's reads.
template <int SGN>
__device__ __forceinline__ void fft_mid_stages(float2* bA, float2* bB,
                                               const float2* __restrict__ tw, int tid) {
#pragma unroll
  for (int st = 1; st < 3; ++st) {
    float2* s = (st == 1) ? bA : bB;
    float2* d = (st == 1) ? bB : bA;
    const int m = 1 << (3 * st);
    __syncthreads();
    const int k  = tid & (m - 1);
    const int jm = tid - k;
    float2 a[8], A[8];
#pragma unroll
    for (int q = 0; q < 8; ++q) a[q] = s[IDX2(tid + 256 * q)];
    bfly8<SGN>(a, A);
    const int base = 8 * jm + k;
    d[IDX2(base)] = A[0];
#pragma unroll
    for (int dd = 1; dd < 8; ++dd) {
      float2 w = tw[dd * jm];
      float wi = (SGN < 0) ? w.y : -w.y;
      d[IDX2(base + dd * m)] = make_float2(A[dd].x * w.x - A[dd].y * wi,
                                           A[dd].x * wi + A[dd].y * w.x);
    }
  }
}

template <int SGN>
__device__ __forceinline__ void fft_final_r4_lds(const float2* s, float2* d, int tid) {
  __syncthreads();
#pragma unroll
  for (int q = 0; q < 2; ++q) {
    const int t = tid + (q << 8);
    float2 x0 = s[IDX2(t)], x1 = s[IDX2(t + 512)];
    float2 x2 = s[IDX2(t + 1024)], x3 = s[IDX2(t + 1536)];
    float2 s0 = cadd(x0, x2), s1 = csub(x0, x2);
    float2 s2 = cadd(x1, x3), s3 = csub(x1, x3);
    float2 mi = (SGN < 0) ? make_float2(s3.y, -s3.x) : make_float2(-s3.y, s3.x);
    d[IDX2(t)]        = cadd(s0, s2);
    d[IDX2(t + 512)]  = cadd(s1, mi);
    d[IDX2(t + 1024)] = csub(s0, s2);
    d[IDX2(t + 1536)] = csub(s1, mi);
  }
  __syncthreads();
}

// final radix-4 to registers: out0 = X[tid + {0,512,1024,1536}],
// out1 = X[tid+256 + {0,512,1024,1536}].
template <int SGN>
__device__ __forceinline__ void fft_final_r4_reg(const float2* s, int tid,
                                                 float2 out0[4], float2 out1[4]) {
  __syncthreads();
#pragma unroll
  for (int q = 0; q < 2; ++q) {
    const int t = tid + (q << 8);
    float2 x0 = s[IDX2(t)], x1 = s[IDX2(t + 512)];
    float2 x2 = s[IDX2(t + 1024)], x3 = s[IDX2(t + 1536)];
    float2 s0 = cadd(x0, x2), s1 = csub(x0, x2);
    float2 s2 = cadd(x1, x3), s3 = csub(x1, x3);
    float2 mi = (SGN < 0) ? make_float2(s3.y, -s3.x) : make_float2(-s3.y, s3.x);
    float2* o = q ? out1 : out0;
    o[0] = cadd(s0, s2);
    o[1] = cadd(s1, mi);
    o[2] = csub(s0, s2);
    o[3] = csub(s1, mi);
  }
}

// setup: twiddles, Win transpose, state projection, weight shuffle into MFMA
// fragment order:
// W1s chunk c: c = cblk*2048 + s*256 + n*64 + lane (cblk<8, s<8, n<4)
// W2s chunk c: c = cblk*2048 + s*128 + n*64 + lane (cblk<8, s<16, n<2)
__global__ __launch_bounds__(256) void k_setup(
    const float* __restrict__ W1, const float* __restrict__ W2, const float* __restrict__ Win,
    const float* __restrict__ init, const float* __restrict__ Wst,
    const float* __restrict__ bst, const float* __restrict__ bin,
    short* __restrict__ W1s, short* __restrict__ W2s, float* __restrict__ WinT,
    float* __restrict__ sp, float2* __restrict__ tw) {
  int idx = blockIdx.x * 256 + threadIdx.x;
  if (idx < 2048) {
    float s, c;
    sincosf(3.14159265358979323846f * (float)idx / 1024.0f, &s, &c);
    tw[idx] = make_float2(c, -s);
  }
  if (idx < 65536) {
    int i = idx >> 14, c = idx & 16383;
    int cblk = c >> 11, s = (c >> 8) & 7, n = (c >> 6) & 3, lane = c & 63;
    int cl = lane & 15, rg = lane >> 4;
    int col = cblk * 64 + n * 16 + cl;
    const float* srcp = W1 + ((size_t)(i * 512 + col)) * 256 + s * 32 + rg * 8;
    short* dstp = W1s + ((size_t)idx) * 8;
#pragma unroll
    for (int j = 0; j < 8; ++j) dstp[j] = f2bf(srcp[j]);
  } else if (idx < 131072) {
    int t = idx - 65536;
    int i = t >> 14, c = t & 16383;
    int cblk = c >> 11, s = (c >> 7) & 15, n = (c >> 6) & 1, lane = c & 63;
    int cl = lane & 15, rg = lane >> 4;
    int col = cblk * 32 + n * 16 + cl;
    const float* srcp = W2 + ((size_t)(i * 256 + col)) * 512 + s * 32 + rg * 8;
    short* dstp = W2s + ((size_t)t) * 8;
#pragma unroll
    for (int j = 0; j < 8; ++j) dstp[j] = f2bf(srcp[j]);
  }
  if (idx < 256 * 64) {
    int hh = idx / 64, c = idx % 64;
    WinT[c * 256 + hh] = Win[idx];
  }
  if (idx < BB * H) {
    int b = idx >> 8, h = idx & 255;
    float acc = bin[h] + bst[h];
#pragma unroll
    for (int c = 0; c < COUT; ++c) acc += init[b * COUT + c] * Wst[h * COUT + c];
    sp[idx] = acc;
  }
}

// Fused input-proj + LN1(layer0): 16 l-rows per block. x stored bf16 row-major.
__global__ __launch_bounds__(256) void k_in_ln1(
    const float* __restrict__ stim, const float* __restrict__ WinT,
    const float* __restrict__ sp, const float* __restrict__ lw, const float* __restrict__ lb,
    short* __restrict__ x, float* __restrict__ xnT) {
  int blk = blockIdx.x;               // b*64 + ltile
  int b_ = blk >> 6, l0 = (blk & 63) << 4;
  int tid = threadIdx.x, wv = tid >> 6, lane = tid & 63;
  __shared__ float sc[16][CIN];
  __shared__ float T[16][256];
#pragma unroll
  for (int it = 0; it < 4; ++it) {
    int idx = tid + (it << 8);
    int r = idx & 15, c = idx >> 4;
    sc[r][c] = stim[(b_ * CIN + c) * LL + l0 + r];
  }
  __syncthreads();
  float4 sp4 = *(const float4*)&sp[b_ * H + lane * 4];
  float4 acc[4] = {sp4, sp4, sp4, sp4};
  for (int c = 0; c < CIN; ++c) {
    float4 wv4 = *(const float4*)&WinT[c * H + lane * 4];
#pragma unroll
    for (int rr = 0; rr < 4; ++rr) {
      float s = sc[wv * 4 + rr][c];
      acc[rr].x += s * wv4.x; acc[rr].y += s * wv4.y;
      acc[rr].z += s * wv4.z; acc[rr].w += s * wv4.w;
    }
  }
  float4 w4 = *(const float4*)&lw[lane * 4];
  float4 c4 = *(const float4*)&lb[lane * 4];
#pragma unroll
  for (int rr = 0; rr < 4; ++rr) {
    int lr = wv * 4 + rr;
    float4 v = acc[rr];
    short4v s4;
    s4[0] = f2bf(v.x); s4[1] = f2bf(v.y); s4[2] = f2bf(v.z); s4[3] = f2bf(v.w);
    *(short4v*)&x[(((size_t)(b_ << 10) + l0 + lr)) * H + lane * 4] = s4;
    float s = v.x + v.y + v.z + v.w;
#pragma unroll
    for (int o = 32; o > 0; o >>= 1) s += __shfl_xor(s, o, 64);
    float m = s * (1.0f / H);
    float dx = v.x - m, dy = v.y - m, dz = v.z - m, dw = v.w - m;
    float q = dx * dx + dy * dy + dz * dz + dw * dw;
#pragma unroll
    for (int o = 32; o > 0; o >>= 1) q += __shfl_xor(q, o, 64);
    float rs = rsqrtf(q * (1.0f / H) + 1e-5f);
    float4 o4;
    o4.x = dx * rs * w4.x + c4.x; o4.y = dy * rs * w4.y + c4.y;
    o4.z = dz * rs * w4.z + c4.z; o4.w = dw * rs * w4.w + c4.w;
    *(float4*)&T[lr][lane * 4] = o4;
  }
  __syncthreads();
  float tmp[16];
#pragma unroll
  for (int l = 0; l < 16; ++l) tmp[l] = T[l][tid];
  float* dst = xnT + ((size_t)(b_ * H + tid)) * LL + l0;
#pragma unroll
  for (int l = 0; l < 16; l += 4) {
    float4 v = {tmp[l], tmp[l + 1], tmp[l + 2], tmp[l + 3]};
    *(float4*)&dst[l] = v;
  }
}

// All layers: blk = i*H + h. K[l] via 2-table lookup; FFT with register
// stage-0 and register final stage (kf written from registers).
__global__ __launch_bounds__(256) void k_kernelfft(
    const float* __restrict__ A_re, const float* __restrict__ A_im,
    const float* __restrict__ C_re, const float* __restrict__ C_im,
    const float* __restrict__ log_step, const float2* __restrict__ tw,
    float2* __restrict__ kf) {
  int blk = blockIdx.x;                 // i*H + h
  int i = blk >> 8;
  int tid = threadIdx.x;
  __shared__ float2 cb[NST], Mv[NST];
  __shared__ float2 bufA[FBUF], bufB[FBUF];
  float2* T1 = bufB;                    // [n][16], overlays FFT scratch
  float2* T2 = bufB + 1024;             // [n][16]
  float step = expf(log_step[blk]);
  int n = tid & 63, g = tid >> 6;
  float Ar = A_re[i * NST + n], Ai = A_im[i * NST + n];
  float dr = step * Ar, di = step * Ai;
  float er = expf(dr);
  float sn, cs; sincosf(di, &sn, &cs);
  float Er = er * cs, Ei = er * sn;     // E = exp(dA)
  if (g == 0) {
    float nr = Er - 1.0f, ni = Ei;
    float dnm = Ar * Ar + Ai * Ai;
    float qr = (nr * Ar + ni * Ai) / dnm;    // (exp(dA)-1)/A
    float qi = (ni * Ar - nr * Ai) / dnm;
    float Cr = C_re[(size_t)blk * NST + n], Ci = C_im[(size_t)blk * NST + n];
    cb[n] = make_float2(Cr * qr - Ci * qi, Cr * qi + Ci * qr);
    float pr = 1.f, pi = 0.f;
    T1[n * 16] = make_float2(1.f, 0.f);
    for (int a = 1; a < 16; ++a) {
      float t2 = pr * Er - pi * Ei; pi = pr * Ei + pi * Er; pr = t2;
      T1[n * 16 + a] = make_float2(pr, pi);
    }
  } else if (g == 1) {
    float xr = Er, xi = Ei;
#pragma unroll
    for (int j = 0; j < 4; ++j) { float t2 = xr * xr - xi * xi; xi = 2.f * xr * xi; xr = t2; }
    float pr = 1.f, pi = 0.f;
    T2[n * 16] = make_float2(1.f, 0.f);
    for (int a = 1; a < 16; ++a) {
      float t2 = pr * xr - pi * xi; pi = pr * xi + pi * xr; pr = t2;
      T2[n * 16 + a] = make_float2(pr, pi);
    }
    float mr2 = pr * xr - pi * xi, mi2 = pr * xi + pi * xr;   // E^256
    Mv[n] = make_float2(mr2, mi2);
  }
  __syncthreads();
  float kr[4] = {0.f, 0.f, 0.f, 0.f}, ki[4] = {0.f, 0.f, 0.f, 0.f};
  const int a_lo = tid & 15, a_hi = tid >> 4;
  for (int nn = 0; nn < NST; ++nn) {
    float2 t1 = T1[nn * 16 + a_lo];
    float2 t2v = T2[nn * 16 + a_hi];
    float pr = t1.x * t2v.x - t1.y * t2v.y;   // E^tid
    float pi = t1.x * t2v.y + t1.y * t2v.x;
    float2 c = cb[nn], m = Mv[nn];
#pragma unroll
    for (int q = 0; q < 4; ++q) {
      kr[q] += c.x * pr - c.y * pi;
      ki[q] += c.x * pi + c.y * pr;
      float t2 = pr * m.x - pi * m.y;         // p *= E^256
      pi = pr * m.y + pi * m.x;
      pr = t2;
    }
  }
  float2 a[8];
#pragma unroll
  for (int q = 0; q < 4; ++q) a[q] = make_float2(kr[q], ki[q]);
  a[4] = a[5] = a[6] = a[7] = make_float2(0.f, 0.f);
  fft_stage0_reg<-1>(a, bufA, tw, tid);
  fft_mid_stages<-1>(bufA, bufB, tw, tid);   // m=8: A->B, m=64: B->A
  float2 F0[4], F1[4];
  fft_final_r4_reg<-1>(bufA, tid, F0, F1);
  float2* kfh = kf + (size_t)blk * 1025;
  kfh[tid]       = F0[0];
  kfh[tid + 512] = F0[1];
  kfh[tid + 256] = F1[0];
  kfh[tid + 768] = F1[1];
  if (tid == 0) kfh[1024] = F0[2];
}

// Two rows packed per complex FFT; register stage-0 in, register final out.
// Spectral multiply FUSED into the inverse stage-0 gather (saves one LDS
// pass + barrier). yT written as bf16.
__global__ __launch_bounds__(256) void k_conv(
    const float* __restrict__ xnT, const float2* __restrict__ kf,
    const float* __restrict__ D, const float2* __restrict__ tw, short* __restrict__ yT) {
  int blk = blockIdx.x;                 // b*128 + hp
  int b_ = blk >> 7, hp = blk & 127;
  int h0 = hp * 2, h1 = h0 + 1;
  int r0 = b_ * H + h0;
  int tid = threadIdx.x;
  __shared__ float2 bufA[FBUF], bufB[FBUF];
  float2 w0[7];
#pragma unroll
  for (int dd = 1; dd < 8; ++dd) w0[dd - 1] = tw[dd * tid];
  float u0[4], u1[4];
  const float* x0 = xnT + (size_t)r0 * LL;
  const float* x1 = x0 + LL;
  float2 a[8];
#pragma unroll
  for (int q = 0; q < 4; ++q) {
    int l = tid + (q << 8);
    float v0 = x0[l], v1 = x1[l];
    u0[q] = v0; u1[q] = v1;
    a[q] = make_float2(v0, v1);
  }
  a[4] = a[5] = a[6] = a[7] = make_float2(0.f, 0.f);
  fft_stage0_reg_tw<-1>(a, bufA, w0, tid);
  fft_mid_stages<-1>(bufA, bufB, tw, tid);   // result of m=64 in bufA
  fft_final_r4_lds<-1>(bufA, bufB, tid);     // spectrum F in bufB (barrier after)
  const float2* kf0 = kf + (size_t)h0 * 1025;
  const float2* kf1 = kf + (size_t)h1 * 1025;
  // fused spectral multiply + inverse stage-0 gather
  float2 g[8];
#pragma unroll
  for (int q = 0; q < 8; ++q) {
    int k = tid + (q << 8);
    float2 Z;
    if (tid == 0 && q == 0) {
      float2 Fz = bufB[IDX2(0)];
      Z = make_float2(Fz.x * kf0[0].x, Fz.y * kf1[0].x);
    } else if (tid == 0 && q == 4) {
      float2 Fn = bufB[IDX2(1024)];
      Z = make_float2(Fn.x * kf0[1024].x, Fn.y * kf1[1024].x);
    } else {
      int km = (k < 1024) ? k : 2048 - k;
      float2 Flo = bufB[IDX2(km)];
      float2 Fhi = bufB[IDX2(2048 - km)];
      float u0r = 0.5f * (Flo.x + Fhi.x), u0i = 0.5f * (Flo.y - Fhi.y);   // U0[km]
      float dr_ = 0.5f * (Flo.x - Fhi.x), di_ = 0.5f * (Flo.y + Fhi.y);
      float u1r = di_, u1i = -dr_;                                        // U1[km]
      float2 k0 = kf0[km], k1 = kf1[km];
      float z0r = u0r * k0.x - u0i * k0.y, z0i = u0r * k0.y + u0i * k0.x;
      float z1r = u1r * k1.x - u1i * k1.y, z1i = u1r * k1.y + u1i * k1.x;
      Z = (k < 1024) ? make_float2(z0r - z1i, z0i + z1r)
                     : make_float2(z0r + z1i, z1r - z0i);
    }
    g[q] = Z;
  }
  fft_stage0_reg_tw<1>(g, bufA, w0, tid);    // writes bufA (reads of bufA done)
  fft_mid_stages<1>(bufA, bufB, tw, tid);    // m=8: A->B, m=64: B->A
  float2 z0[4], z1[4];
  fft_final_r4_reg<1>(bufA, tid, z0, z1);
  float Dh0 = D[h0], Dh1 = D[h1];
  short* y0 = yT + (size_t)r0 * LL;
  short* y1 = y0 + LL;
  const float s = 1.0f / NFFT;
  y0[tid]       = f2bf(z0[0].x * s + Dh0 * u0[0]);
  y0[tid + 256] = f2bf(z1[0].x * s + Dh0 * u0[1]);
  y0[tid + 512] = f2bf(z0[1].x * s + Dh0 * u0[2]);
  y0[tid + 768] = f2bf(z1[1].x * s + Dh0 * u0[3]);
  y1[tid]       = f2bf(z0[0].y * s + Dh1 * u1[0]);
  y1[tid + 256] = f2bf(z1[0].y * s + Dh1 * u1[1]);
  y1[tid + 512] = f2bf(z0[1].y * s + Dh1 * u1[2]);
  y1[tid + 768] = f2bf(z1[1].y * s + Dh1 * u1[3]);
}

// ---------------------------------------------------------------------------
// Mega MLP kernel, 512 threads, 16-row tile, grid 512 -> 2 blocks/CU.
// x row-major bf16 (coalesced 16-lane segments), yT transposed bf16.
// GEMM1 s=0,1 prefetched before Phase A; GEMM2 s=0,1 prefetched before the
// GELU epilogue; setprio around MFMA clusters.
// LDS: A1[16][264]s @0 | A2[16][520]s @8448 | red @25088
//      LAST: Txn[16][260]f @0, wlds[8][258]f @16896
// ---------------------------------------------------------------------------
#define TXS 260
template <bool LAST>
__global__ __launch_bounds__(512, 4) void k_mlp(
    const short* __restrict__ W1p, const float* __restrict__ b1p,
    const short* __restrict__ W2p, const float* __restrict__ b2p,
    short* __restrict__ x, const short* __restrict__ yT,
    const float* __restrict__ ln2w, const float* __restrict__ ln2b,
    const float* __restrict__ ln1w, const float* __restrict__ ln1b,
    float* __restrict__ xnT,
    const float* __restrict__ Wout, const float* __restrict__ bout,
    float* __restrict__ out) {
  const int m0 = blockIdx.x * 16;
  const int b_ = m0 >> 10, l0 = m0 & 1023;
  const int tid = threadIdx.x;
  const int lane = tid & 63, wid = tid >> 6;       // 8 waves
  const int rg = lane >> 4, cl = lane & 15;
  __shared__ __attribute__((aligned(16))) char smem[26112];
  short* A1  = (short*)smem;                 // [16][264]
  short* A2  = (short*)(smem + 8448);        // [16][520]
  float* red = (float*)(smem + 25088);       // [8][16][2]
  float* Txn = (float*)smem;                 // [16][260] (LAST)
  float* wlds = (float*)(smem + 16896);      // [8][258]  (LAST)

  const short* w1base = W1p + (size_t)wid * 16384 + lane * 8;
  const short* w2base = W2p + (size_t)wid * 16384 + lane * 8;
  // prefetch GEMM1 s=0,1 fragments — hides L2 latency under Phase A
  bf16x8 pre[8];
#pragma unroll
  for (int n = 0; n < 8; ++n)
    pre[n] = *(const bf16x8*)(w1base + n * 512);

  // ---- Phase A: residual add (registers) + LN2 -> A1 bf16 ----
  float v[2][4];                             // [n][r], rows rg*4+r
  float wl2[2], bl2[2];
#pragma unroll
  for (int n = 0; n < 2; ++n) {
    int col = wid * 32 + n * 16 + cl;
    wl2[n] = ln2w[col]; bl2[n] = ln2b[col];
  }
  float sum[4], sq[4];
#pragma unroll
  for (int r = 0; r < 4; ++r) { sum[r] = 0.f; sq[r] = 0.f; }
#pragma unroll
  for (int n = 0; n < 2; ++n) {
    int col = wid * 32 + n * 16 + cl;
    short4v y4 = *(const short4v*)&yT[((size_t)(b_ * H + col)) * LL + l0 + rg * 4];
    float yv[4] = {b2f(y4[0]), b2f(y4[1]), b2f(y4[2]), b2f(y4[3])};
#pragma unroll
    for (int r = 0; r < 4; ++r) {
      int row = rg * 4 + r;
      float val = b2f(x[(size_t)(m0 + row) * H + col]) + yv[r];
      v[n][r] = val;
      sum[r] += val; sq[r] += val * val;
    }
  }
#pragma unroll
  for (int r = 0; r < 4; ++r) {
#pragma unroll
    for (int o = 1; o < 16; o <<= 1) {
      sum[r] += __shfl_xor(sum[r], o, 64);
      sq[r]  += __shfl_xor(sq[r], o, 64);
    }
  }
  if (cl == 0) {
#pragma unroll
    for (int r = 0; r < 4; ++r) {
      int row = rg * 4 + r;
      red[(wid * 16 + row) * 2]     = sum[r];
      red[(wid * 16 + row) * 2 + 1] = sq[r];
    }
  }
  __syncthreads();
#pragma unroll
  for (int r = 0; r < 4; ++r) {
    int row = rg * 4 + r;
    float S = 0.f, Q = 0.f;
#pragma unroll
    for (int w = 0; w < 8; ++w) { S += red[(w * 16 + row) * 2]; Q += red[(w * 16 + row) * 2 + 1]; }
    float mean = S * (1.0f / H);
    float var = Q * (1.0f / H) - mean * mean;
    float rs = rsqrtf(var + 1e-5f);
#pragma unroll
    for (int n = 0; n < 2; ++n) {
      int col = wid * 32 + n * 16 + cl;
      A1[row * 264 + col] = f2bf((v[n][r] - mean) * rs * wl2[n] + bl2[n]);
    }
  }
  __syncthreads();   // A1 complete; K-loops below are barrier-free

  // ---- Phase B: GEMM1 (16x512, K=256); wave w -> cols w*64..w*64+63 ----
  f32x4 acc1[4];
#pragma unroll
  for (int n = 0; n < 4; ++n) acc1[n] = (f32x4){0.f, 0.f, 0.f, 0.f};
  {
#pragma unroll
    for (int s = 0; s < 8; ++s) {
      const int kk = s * 32;
      bf16x8 af, bfv[4];
      if (s < 2) {
#pragma unroll
        for (int n = 0; n < 4; ++n) bfv[n] = pre[s * 4 + n];
      } else {
#pragma unroll
        for (int n = 0; n < 4; ++n)
          bfv[n] = *(const bf16x8*)(w1base + (s * 4 + n) * 512);
      }
      af = *(const bf16x8*)&A1[cl * 264 + kk + rg * 8];
      __builtin_amdgcn_s_setprio(1);
#pragma unroll
      for (int n = 0; n < 4; ++n)
        acc1[n] = __builtin_amdgcn_mfma_f32_16x16x32_bf16(af, bfv[n], acc1[n], 0, 0, 0);
      __builtin_amdgcn_s_setprio(0);
    }
  }
  // prefetch GEMM2 s=0,1 — hides W2 L2 latency under GELU epilogue + barrier
  bf16x8 pre2[4];
#pragma unroll
  for (int n = 0; n < 4; ++n)
    pre2[n] = *(const bf16x8*)(w2base + n * 512);
  // +b1, GELU -> A2 bf16
#pragma unroll
  for (int n = 0; n < 4; ++n) {
    int col = wid * 64 + n * 16 + cl;
    float bb = b1p[col];
#pragma unroll
    for (int r = 0; r < 4; ++r) {
      int row = rg * 4 + r;
      float g = acc1[n][r] + bb;
      g = 0.5f * g * (1.0f + erff(g * 0.70710678118654752f));
      A2[row * 520 + col] = f2bf(g);
    }
  }
  __syncthreads();   // A2 complete

  // ---- Phase C: GEMM2 (16x256, K=512); wave w -> cols w*32..w*32+31 ----
  f32x4 acc2[2];
#pragma unroll
  for (int n = 0; n < 2; ++n) acc2[n] = (f32x4){0.f, 0.f, 0.f, 0.f};
  {
#pragma unroll
    for (int s = 0; s < 16; ++s) {
      const int kk = s * 32;
      bf16x8 af, bfv[2];
      if (s < 2) {
#pragma unroll
        for (int n = 0; n < 2; ++n) bfv[n] = pre2[s * 2 + n];
      } else {
#pragma unroll
        for (int n = 0; n < 2; ++n)
          bfv[n] = *(const bf16x8*)(w2base + (s * 2 + n) * 512);
      }
      af = *(const bf16x8*)&A2[cl * 520 + kk + rg * 8];
      __builtin_amdgcn_s_setprio(1);
#pragma unroll
      for (int n = 0; n < 2; ++n)
        acc2[n] = __builtin_amdgcn_mfma_f32_16x16x32_bf16(af, bfv[n], acc2[n], 0, 0, 0);
      __builtin_amdgcn_s_setprio(0);
    }
  }

  // ---- Phase D: vf = acc2 + b2 + v; LN1-next + xnT | output proj ----
  float bv[2], wl1[2], bl1[2];
#pragma unroll
  for (int n = 0; n < 2; ++n) {
    int col = wid * 32 + n * 16 + cl;
    bv[n] = b2p[col];
    if (!LAST) { wl1[n] = ln1w[col]; bl1[n] = ln1b[col]; }
  }
#pragma unroll
  for (int r = 0; r < 4; ++r) { sum[r] = 0.f; sq[r] = 0.f; }
#pragma unroll
  for (int n = 0; n < 2; ++n) {
#pragma unroll
    for (int r = 0; r < 4; ++r) {
      float vf = acc2[n][r] + bv[n] + v[n][r];
      acc2[n][r] = vf;
      sum[r] += vf; sq[r] += vf * vf;
    }
  }

  if (LAST) {
    __syncthreads();   // all waves done reading A2 before Txn overlays it
#pragma unroll
    for (int n = 0; n < 2; ++n) {
      int col = wid * 32 + n * 16 + cl;
#pragma unroll
      for (int r = 0; r < 4; ++r) {
        int row = rg * 4 + r;
        Txn[row * TXS + col] = acc2[n][r];
      }
    }
#pragma unroll
    for (int it = 0; it < 4; ++it) {
      int idx = tid + (it << 9);
      wlds[(idx >> 8) * 258 + (idx & 255)] = Wout[idx];
    }
    __syncthreads();
    if (tid < 128) {
      int row = tid >> 3, co = tid & 7;
      float p = bout[co];
      const float* tr = Txn + row * TXS;
      const float* wr = wlds + co * 258;
#pragma unroll 4
      for (int c = 0; c < H; ++c) p += tr[c] * wr[c];
      out[((b_ * COUT + co) << 10) + l0 + row] = p;
    }
  } else {
#pragma unroll
    for (int r = 0; r < 4; ++r) {
#pragma unroll
      for (int o = 1; o < 16; o <<= 1) {
        sum[r] += __shfl_xor(sum[r], o, 64);
        sq[r]  += __shfl_xor(sq[r], o, 64);
      }
    }
    if (cl == 0) {
#pragma unroll
      for (int r = 0; r < 4; ++r) {
        int row = rg * 4 + r;
        red[(wid * 16 + row) * 2]     = sum[r];
        red[(wid * 16 + row) * 2 + 1] = sq[r];
      }
    }
    __syncthreads();   // red ready AND all waves done with A1/A2 (Txn safe)
#pragma unroll
    for (int r = 0; r < 4; ++r) {
      int row = rg * 4 + r;
      float S = 0.f, Q = 0.f;
#pragma unroll
      for (int w = 0; w < 8; ++w) { S += red[(w * 16 + row) * 2]; Q += red[(w * 16 + row) * 2 + 1]; }
      float mean = S * (1.0f / H);
      float var = Q * (1.0f / H) - mean * mean;
      float rs = rsqrtf(var + 1e-5f);
#pragma unroll
      for (int n = 0; n < 2; ++n) {
        int col = wid * 32 + n * 16 + cl;
        float vf = acc2[n][r];
        x[(size_t)(m0 + row) * H + col] = f2bf(vf);
        Txn[row * TXS + col] = (vf - mean) * rs * wl1[n] + bl1[n];
      }
    }
    __syncthreads();
    // transposed copy: 512 threads, each moves 8 l-contiguous floats
    int h = tid & 255, seg = (tid >> 8) * 8;
    float tmp[8];
#pragma unroll
    for (int l = 0; l < 8; ++l) tmp[l] = Txn[(seg + l) * TXS + h];
    float* dst = xnT + ((size_t)(b_ * H + h)) * LL + l0 + seg;
#pragma unroll
    for (int l = 0; l < 8; l += 4) {
      float4 v4 = {tmp[l], tmp[l + 1], tmp[l + 2], tmp[l + 3]};
      *(float4*)&dst[l] = v4;
    }
  }
}

extern "C" void kernel_launch(void* const* d_in, const int* in_sizes, int n_in,
                              void* d_out, int out_size, void* d_ws, size_t ws_size,
                              hipStream_t stream) {
  const float* stim  = (const float*)d_in[0];
  const float* init  = (const float*)d_in[1];
  const float* A_re  = (const float*)d_in[2];
  const float* A_im  = (const float*)d_in[3];
  const float* C_re  = (const float*)d_in[4];
  const float* C_im  = (const float*)d_in[5];
  const float* Dp    = (const float*)d_in[6];
  const float* lstep = (const float*)d_in[7];
  const float* ln1w  = (const float*)d_in[8];
  const float* ln1b  = (const float*)d_in[9];
  const float* ln2w  = (const float*)d_in[10];
  const float* ln2b  = (const float*)d_in[11];
  const float* W1    = (const float*)d_in[12];
  const float* b1    = (const float*)d_in[13];
  const float* W2    = (const float*)d_in[14];
  const float* b2    = (const float*)d_in[15];
  const float* Win   = (const float*)d_in[16];
  const float* bin   = (const float*)d_in[17];
  const float* Wst   = (const float*)d_in[18];
  const float* bst   = (const float*)d_in[19];
  const float* Wout  = (const float*)d_in[20];
  const float* bout  = (const float*)d_in[21];
  float* out = (float*)d_out;
  float* ws = (float*)d_ws;

  size_t o = 0;
  auto alloc = [&](size_t nfloats) { size_t r = o; o += (nfloats + 63) & ~(size_t)63; return r; };
  short*  x    = (short*)(ws + alloc((size_t)BB * LL * H / 2));
  float*  xnT  = ws + alloc((size_t)BB * H * LL);
  short*  yT   = (short*)(ws + alloc((size_t)BB * H * LL / 2));
  float2* kf   = (float2*)(ws + alloc((size_t)NL * H * 1025 * 2));
  short*  W1s  = (short*)(ws + alloc((size_t)NL * 512 * 256 / 2));
  short*  W2s  = (short*)(ws + alloc((size_t)NL * 256 * 512 / 2));
  float*  WinT = ws + alloc((size_t)64 * 256);
  float*  sp   = ws + alloc((size_t)BB * H);
  float2* tw   = (float2*)(ws + alloc((size_t)2048 * 2));
  (void)ws_size; (void)in_sizes; (void)n_in; (void)out_size;

  k_setup<<<512, 256, 0, stream>>>(W1, W2, Win, init, Wst, bst, bin,
                                   W1s, W2s, WinT, sp, tw);
  k_kernelfft<<<NL * H, 256, 0, stream>>>(A_re, A_im, C_re, C_im, lstep, tw, kf);
  k_in_ln1<<<BB * 64, 256, 0, stream>>>(stim, WinT, sp, ln1w, ln1b, x, xnT);

  for (int i = 0; i < NL; ++i) {
    k_conv<<<BB * H / 2, 256, 0, stream>>>(xnT, kf + (size_t)i * H * 1025,
                                           Dp + i * H, tw, yT);
    if (i < NL - 1) {
      k_mlp<false><<<512, 512, 0, stream>>>(
          W1s + (size_t)i * 512 * 256, b1 + i * 512,
          W2s + (size_t)i * 256 * 512, b2 + i * H,
          x, yT, ln2w + i * H, ln2b + i * H,
          ln1w + (i + 1) * H, ln1b + (i + 1) * H, xnT,
          nullptr, nullptr, nullptr);
    } else {
      k_mlp<true><<<512, 512, 0, stream>>>(
          W1s + (size_t)i * 512 * 256, b1 + i * 512,
          W2s + (size_t)i * 256 * 512, b2 + i * H,
          x, yT, ln2w + i * H, ln2b + i * H,
          nullptr, nullptr, nullptr,
          Wout, bout, out);
    }
  }
}

// Round 18
// 175.894 us; speedup vs baseline: 1.0722x; 1.0358x over previous
//
#include <hip/hip_runtime.h>
#include <math.h>

#define NL   4
#define H    256
#define NST  64
#define CIN  64
#define COUT 8
#define BB   8
#define LL   1024
#define NFFT 2048

typedef __attribute__((ext_vector_type(8))) short bf16x8;
typedef __attribute__((ext_vector_type(4))) short short4v;
typedef __attribute__((ext_vector_type(4))) int   int4v;
typedef __attribute__((ext_vector_type(4))) float f32x4;

__device__ __forceinline__ short f2bf(float f) {
  union { float f; unsigned u; } v; v.f = f;
  unsigned r = (v.u + 0x7fffu + ((v.u >> 16) & 1u)) >> 16;
  return (short)r;
}
__device__ __forceinline__ float b2f(short s) {
  union { unsigned u; float f; } v;
  v.u = ((unsigned)(unsigned short)s) << 16;
  return v.f;
}
__device__ __forceinline__ int IDX2(int a) { return a + (a >> 4); }
#define FBUF 2176   // 2048 + 128 pad

__device__ __forceinline__ float2 cadd(float2 a, float2 b) { return make_float2(a.x + b.x, a.y + b.y); }
__device__ __forceinline__ float2 csub(float2 a, float2 b) { return make_float2(a.x - b.x, a.y - b.y); }

// ---------------------------------------------------------------------------
// 2048-pt FFT pieces (Stockham radix-8 x3 + final radix-4), float2 LDS.
// ---------------------------------------------------------------------------
template <int SGN>
__device__ __forceinline__ void bfly8(const float2 a[8], float2 A[8]) {
  const float RH = 0.70710678118654752f;
  float2 s0 = cadd(a[0], a[4]), s1 = csub(a[0], a[4]);
  float2 s2 = cadd(a[2], a[6]), s3 = csub(a[2], a[6]);
  float2 mi = (SGN < 0) ? make_float2(s3.y, -s3.x) : make_float2(-s3.y, s3.x);
  float2 E0 = cadd(s0, s2), E1 = cadd(s1, mi), E2 = csub(s0, s2), E3 = csub(s1, mi);
  float2 t0 = cadd(a[1], a[5]), t1 = csub(a[1], a[5]);
  float2 t2 = cadd(a[3], a[7]), t3 = csub(a[3], a[7]);
  float2 mj = (SGN < 0) ? make_float2(t3.y, -t3.x) : make_float2(-t3.y, t3.x);
  float2 O0 = cadd(t0, t2), O1 = cadd(t1, mj), O2 = csub(t0, t2), O3 = csub(t1, mj);
  float2 W0 = O0;
  float2 W1 = (SGN < 0) ? make_float2((O1.x + O1.y) * RH, (O1.y - O1.x) * RH)
                        : make_float2((O1.x - O1.y) * RH, (O1.x + O1.y) * RH);
  float2 W2 = (SGN < 0) ? make_float2(O2.y, -O2.x) : make_float2(-O2.y, O2.x);
  float2 W3 = (SGN < 0) ? make_float2((O3.y - O3.x) * RH, -(O3.x + O3.y) * RH)
                        : make_float2(-(O3.x + O3.y) * RH, (O3.x - O3.y) * RH);
  A[0] = cadd(E0, W0); A[4] = csub(E0, W0);
  A[1] = cadd(E1, W1); A[5] = csub(E1, W1);
  A[2] = cadd(E2, W2); A[6] = csub(E2, W2);
  A[3] = cadd(E3, W3); A[7] = csub(E3, W3);
}

// stage 0 via tw pointer (kernelfft path)
template <int SGN>
__device__ __forceinline__ void fft_stage0_reg(const float2 a[8], float2* d,
                                               const float2* __restrict__ tw, int tid) {
  float2 A[8];
  bfly8<SGN>(a, A);
  const int base = 8 * tid;
  d[IDX2(base)] = A[0];
#pragma unroll
  for (int dd = 1; dd < 8; ++dd) {
    float2 w = tw[dd * tid];
    float wi = (SGN < 0) ? w.y : -w.y;
    d[IDX2(base + dd)] = make_float2(A[dd].x * w.x - A[dd].y * wi,
                                     A[dd].x * wi + A[dd].y * w.x);
  }
}

// stage 0 via preloaded per-thread twiddles w[dd-1] = tw[dd*tid] (conv path).
template <int SGN>
__device__ __forceinline__ void fft_stage0_reg_tw(const float2 a[8], float2* d,
                                                  const float2 w[7], int tid) {
  float2 A[8];
  bfly8<SGN>(a, A);
  const int base = 8 * tid;
  d[IDX2(base)] = A[0];
#pragma unroll
  for (int dd = 1; dd < 8; ++dd) {
    float wr = w[dd - 1].x;
    float wi = (SGN < 0) ? w[dd - 1].y : -w[dd - 1].y;
    d[IDX2(base + dd)] = make_float2(A[dd].x * wr - A[dd].y * wi,
                                     A[dd].x * wi + A[dd].y * wr);
  }
}

// stages m=8 (bA->bB) and m=64 (bB->bA); barrier before each stage's reads.
template <int SGN>
__device__ __forceinline__ void fft_mid_stages(float2* bA, float2* bB,
                                               const float2* __restrict__ tw, int tid) {
#pragma unroll
  for (int st = 1; st < 3; ++st) {
    float2* s = (st == 1) ? bA : bB;
    float2* d = (st == 1) ? bB : bA;
    const int m = 1 << (3 * st);
    __syncthreads();
    const int k  = tid & (m - 1);
    const int jm = tid - k;
    float2 a[8], A[8];
#pragma unroll
    for (int q = 0; q < 8; ++q) a[q] = s[IDX2(tid + 256 * q)];
    bfly8<SGN>(a, A);
    const int base = 8 * jm + k;
    d[IDX2(base)] = A[0];
#pragma unroll
    for (int dd = 1; dd < 8; ++dd) {
      float2 w = tw[dd * jm];
      float wi = (SGN < 0) ? w.y : -w.y;
      d[IDX2(base + dd * m)] = make_float2(A[dd].x * w.x - A[dd].y * wi,
                                           A[dd].x * wi + A[dd].y * w.x);
    }
  }
}

template <int SGN>
__device__ __forceinline__ void fft_final_r4_lds(const float2* s, float2* d, int tid) {
  __syncthreads();
#pragma unroll
  for (int q = 0; q < 2; ++q) {
    const int t = tid + (q << 8);
    float2 x0 = s[IDX2(t)], x1 = s[IDX2(t + 512)];
    float2 x2 = s[IDX2(t + 1024)], x3 = s[IDX2(t + 1536)];
    float2 s0 = cadd(x0, x2), s1 = csub(x0, x2);
    float2 s2 = cadd(x1, x3), s3 = csub(x1, x3);
    float2 mi = (SGN < 0) ? make_float2(s3.y, -s3.x) : make_float2(-s3.y, s3.x);
    d[IDX2(t)]        = cadd(s0, s2);
    d[IDX2(t + 512)]  = cadd(s1, mi);
    d[IDX2(t + 1024)] = csub(s0, s2);
    d[IDX2(t + 1536)] = csub(s1, mi);
  }
  __syncthreads();
}

// final radix-4 to registers: out0 = X[tid + {0,512,1024,1536}],
// out1 = X[tid+256 + {0,512,1024,1536}].
template <int SGN>
__device__ __forceinline__ void fft_final_r4_reg(const float2* s, int tid,
                                                 float2 out0[4], float2 out1[4]) {
  __syncthreads();
#pragma unroll
  for (int q = 0; q < 2; ++q) {
    const int t = tid + (q << 8);
    float2 x0 = s[IDX2(t)], x1 = s[IDX2(t + 512)];
    float2 x2 = s[IDX2(t + 1024)], x3 = s[IDX2(t + 1536)];
    float2 s0 = cadd(x0, x2), s1 = csub(x0, x2);
    float2 s2 = cadd(x1, x3), s3 = csub(x1, x3);
    float2 mi = (SGN < 0) ? make_float2(s3.y, -s3.x) : make_float2(-s3.y, s3.x);
    float2* o = q ? out1 : out0;
    o[0] = cadd(s0, s2);
    o[1] = cadd(s1, mi);
    o[2] = csub(s0, s2);
    o[3] = csub(s1, mi);
  }
}

// setup: twiddles, Win transpose, state projection, weight shuffle into MFMA
// fragment order:
// W1s chunk c: c = cblk*2048 + s*256 + n*64 + lane (cblk<8, s<8, n<4)
// W2s chunk c: c = cblk*2048 + s*128 + n*64 + lane (cblk<8, s<16, n<2)
__global__ __launch_bounds__(256) void k_setup(
    const float* __restrict__ W1, const float* __restrict__ W2, const float* __restrict__ Win,
    const float* __restrict__ init, const float* __restrict__ Wst,
    const float* __restrict__ bst, const float* __restrict__ bin,
    short* __restrict__ W1s, short* __restrict__ W2s, float* __restrict__ WinT,
    float* __restrict__ sp, float2* __restrict__ tw) {
  int idx = blockIdx.x * 256 + threadIdx.x;
  if (idx < 2048) {
    float s, c;
    sincosf(3.14159265358979323846f * (float)idx / 1024.0f, &s, &c);
    tw[idx] = make_float2(c, -s);
  }
  if (idx < 65536) {
    int i = idx >> 14, c = idx & 16383;
    int cblk = c >> 11, s = (c >> 8) & 7, n = (c >> 6) & 3, lane = c & 63;
    int cl = lane & 15, rg = lane >> 4;
    int col = cblk * 64 + n * 16 + cl;
    const float* srcp = W1 + ((size_t)(i * 512 + col)) * 256 + s * 32 + rg * 8;
    short* dstp = W1s + ((size_t)idx) * 8;
#pragma unroll
    for (int j = 0; j < 8; ++j) dstp[j] = f2bf(srcp[j]);
  } else if (idx < 131072) {
    int t = idx - 65536;
    int i = t >> 14, c = t & 16383;
    int cblk = c >> 11, s = (c >> 7) & 15, n = (c >> 6) & 1, lane = c & 63;
    int cl = lane & 15, rg = lane >> 4;
    int col = cblk * 32 + n * 16 + cl;
    const float* srcp = W2 + ((size_t)(i * 256 + col)) * 512 + s * 32 + rg * 8;
    short* dstp = W2s + ((size_t)t) * 8;
#pragma unroll
    for (int j = 0; j < 8; ++j) dstp[j] = f2bf(srcp[j]);
  }
  if (idx < 256 * 64) {
    int hh = idx / 64, c = idx % 64;
    WinT[c * 256 + hh] = Win[idx];
  }
  if (idx < BB * H) {
    int b = idx >> 8, h = idx & 255;
    float acc = bin[h] + bst[h];
#pragma unroll
    for (int c = 0; c < COUT; ++c) acc += init[b * COUT + c] * Wst[h * COUT + c];
    sp[idx] = acc;
  }
}

// Fused input-proj + LN1(layer0): 16 l-rows per block. x stored bf16.
__global__ __launch_bounds__(256) void k_in_ln1(
    const float* __restrict__ stim, const float* __restrict__ WinT,
    const float* __restrict__ sp, const float* __restrict__ lw, const float* __restrict__ lb,
    short* __restrict__ x, float* __restrict__ xnT) {
  int blk = blockIdx.x;               // b*64 + ltile
  int b_ = blk >> 6, l0 = (blk & 63) << 4;
  int tid = threadIdx.x, wv = tid >> 6, lane = tid & 63;
  __shared__ float sc[16][CIN];
  __shared__ float T[16][256];
#pragma unroll
  for (int it = 0; it < 4; ++it) {
    int idx = tid + (it << 8);
    int r = idx & 15, c = idx >> 4;
    sc[r][c] = stim[(b_ * CIN + c) * LL + l0 + r];
  }
  __syncthreads();
  float4 sp4 = *(const float4*)&sp[b_ * H + lane * 4];
  float4 acc[4] = {sp4, sp4, sp4, sp4};
  for (int c = 0; c < CIN; ++c) {
    float4 wv4 = *(const float4*)&WinT[c * H + lane * 4];
#pragma unroll
    for (int rr = 0; rr < 4; ++rr) {
      float s = sc[wv * 4 + rr][c];
      acc[rr].x += s * wv4.x; acc[rr].y += s * wv4.y;
      acc[rr].z += s * wv4.z; acc[rr].w += s * wv4.w;
    }
  }
  float4 w4 = *(const float4*)&lw[lane * 4];
  float4 c4 = *(const float4*)&lb[lane * 4];
#pragma unroll
  for (int rr = 0; rr < 4; ++rr) {
    int lr = wv * 4 + rr;
    float4 v = acc[rr];
    short4v s4;
    s4[0] = f2bf(v.x); s4[1] = f2bf(v.y); s4[2] = f2bf(v.z); s4[3] = f2bf(v.w);
    *(short4v*)&x[(((size_t)(b_ << 10) + l0 + lr)) * H + lane * 4] = s4;
    float s = v.x + v.y + v.z + v.w;
#pragma unroll
    for (int o = 32; o > 0; o >>= 1) s += __shfl_xor(s, o, 64);
    float m = s * (1.0f / H);
    float dx = v.x - m, dy = v.y - m, dz = v.z - m, dw = v.w - m;
    float q = dx * dx + dy * dy + dz * dz + dw * dw;
#pragma unroll
    for (int o = 32; o > 0; o >>= 1) q += __shfl_xor(q, o, 64);
    float rs = rsqrtf(q * (1.0f / H) + 1e-5f);
    float4 o4;
    o4.x = dx * rs * w4.x + c4.x; o4.y = dy * rs * w4.y + c4.y;
    o4.z = dz * rs * w4.z + c4.z; o4.w = dw * rs * w4.w + c4.w;
    *(float4*)&T[lr][lane * 4] = o4;
  }
  __syncthreads();
  float tmp[16];
#pragma unroll
  for (int l = 0; l < 16; ++l) tmp[l] = T[l][tid];
  float* dst = xnT + ((size_t)(b_ * H + tid)) * LL + l0;
#pragma unroll
  for (int l = 0; l < 16; l += 4) {
    float4 v = {tmp[l], tmp[l + 1], tmp[l + 2], tmp[l + 3]};
    *(float4*)&dst[l] = v;
  }
}

// All layers: blk = i*H + h. K[l] via 2-table lookup; FFT with register
// stage-0 and register final stage (kf written from registers).
__global__ __launch_bounds__(256) void k_kernelfft(
    const float* __restrict__ A_re, const float* __restrict__ A_im,
    const float* __restrict__ C_re, const float* __restrict__ C_im,
    const float* __restrict__ log_step, const float2* __restrict__ tw,
    float2* __restrict__ kf) {
  int blk = blockIdx.x;                 // i*H + h
  int i = blk >> 8;
  int tid = threadIdx.x;
  __shared__ float2 cb[NST], Mv[NST];
  __shared__ float2 bufA[FBUF], bufB[FBUF];
  float2* T1 = bufB;                    // [n][16], overlays FFT scratch
  float2* T2 = bufB + 1024;             // [n][16]
  float step = expf(log_step[blk]);
  int n = tid & 63, g = tid >> 6;
  float Ar = A_re[i * NST + n], Ai = A_im[i * NST + n];
  float dr = step * Ar, di = step * Ai;
  float er = expf(dr);
  float sn, cs; sincosf(di, &sn, &cs);
  float Er = er * cs, Ei = er * sn;     // E = exp(dA)
  if (g == 0) {
    float nr = Er - 1.0f, ni = Ei;
    float dnm = Ar * Ar + Ai * Ai;
    float qr = (nr * Ar + ni * Ai) / dnm;    // (exp(dA)-1)/A
    float qi = (ni * Ar - nr * Ai) / dnm;
    float Cr = C_re[(size_t)blk * NST + n], Ci = C_im[(size_t)blk * NST + n];
    cb[n] = make_float2(Cr * qr - Ci * qi, Cr * qi + Ci * qr);
    float pr = 1.f, pi = 0.f;
    T1[n * 16] = make_float2(1.f, 0.f);
    for (int a = 1; a < 16; ++a) {
      float t2 = pr * Er - pi * Ei; pi = pr * Ei + pi * Er; pr = t2;
      T1[n * 16 + a] = make_float2(pr, pi);
    }
  } else if (g == 1) {
    float xr = Er, xi = Ei;
#pragma unroll
    for (int j = 0; j < 4; ++j) { float t2 = xr * xr - xi * xi; xi = 2.f * xr * xi; xr = t2; }
    float pr = 1.f, pi = 0.f;
    T2[n * 16] = make_float2(1.f, 0.f);
    for (int a = 1; a < 16; ++a) {
      float t2 = pr * xr - pi * xi; pi = pr * xi + pi * xr; pr = t2;
      T2[n * 16 + a] = make_float2(pr, pi);
    }
    float mr2 = pr * xr - pi * xi, mi2 = pr * xi + pi * xr;   // E^256
    Mv[n] = make_float2(mr2, mi2);
  }
  __syncthreads();
  float kr[4] = {0.f, 0.f, 0.f, 0.f}, ki[4] = {0.f, 0.f, 0.f, 0.f};
  const int a_lo = tid & 15, a_hi = tid >> 4;
  for (int nn = 0; nn < NST; ++nn) {
    float2 t1 = T1[nn * 16 + a_lo];
    float2 t2v = T2[nn * 16 + a_hi];
    float pr = t1.x * t2v.x - t1.y * t2v.y;   // E^tid
    float pi = t1.x * t2v.y + t1.y * t2v.x;
    float2 c = cb[nn], m = Mv[nn];
#pragma unroll
    for (int q = 0; q < 4; ++q) {
      kr[q] += c.x * pr - c.y * pi;
      ki[q] += c.x * pi + c.y * pr;
      float t2 = pr * m.x - pi * m.y;         // p *= E^256
      pi = pr * m.y + pi * m.x;
      pr = t2;
    }
  }
  float2 a[8];
#pragma unroll
  for (int q = 0; q < 4; ++q) a[q] = make_float2(kr[q], ki[q]);
  a[4] = a[5] = a[6] = a[7] = make_float2(0.f, 0.f);
  fft_stage0_reg<-1>(a, bufA, tw, tid);
  fft_mid_stages<-1>(bufA, bufB, tw, tid);   // m=8: A->B, m=64: B->A
  float2 F0[4], F1[4];
  fft_final_r4_reg<-1>(bufA, tid, F0, F1);
  float2* kfh = kf + (size_t)blk * 1025;
  kfh[tid]       = F0[0];
  kfh[tid + 512] = F0[1];
  kfh[tid + 256] = F1[0];
  kfh[tid + 768] = F1[1];
  if (tid == 0) kfh[1024] = F0[2];
}

// Two rows packed per complex FFT; register stage-0 in, register final out.
// Stage-0 twiddles preloaded once; yT written as bf16. Unfused spectral pass
// (each thread computes 4 products and writes k + mirror — fused variant
// doubles the VALU work and measured slower, r17).
__global__ __launch_bounds__(256) void k_conv(
    const float* __restrict__ xnT, const float2* __restrict__ kf,
    const float* __restrict__ D, const float2* __restrict__ tw, short* __restrict__ yT) {
  int blk = blockIdx.x;                 // b*128 + hp
  int b_ = blk >> 7, hp = blk & 127;
  int h0 = hp * 2, h1 = h0 + 1;
  int r0 = b_ * H + h0;
  int tid = threadIdx.x;
  __shared__ float2 bufA[FBUF], bufB[FBUF];
  float2 w0[7];
#pragma unroll
  for (int dd = 1; dd < 8; ++dd) w0[dd - 1] = tw[dd * tid];
  float u0[4], u1[4];
  const float* x0 = xnT + (size_t)r0 * LL;
  const float* x1 = x0 + LL;
  float2 a[8];
#pragma unroll
  for (int q = 0; q < 4; ++q) {
    int l = tid + (q << 8);
    float v0 = x0[l], v1 = x1[l];
    u0[q] = v0; u1[q] = v1;
    a[q] = make_float2(v0, v1);
  }
  a[4] = a[5] = a[6] = a[7] = make_float2(0.f, 0.f);
  fft_stage0_reg_tw<-1>(a, bufA, w0, tid);
  fft_mid_stages<-1>(bufA, bufB, tw, tid);   // result of m=64 in bufA
  fft_final_r4_lds<-1>(bufA, bufB, tid);     // spectrum F in bufB
  const float2* kf0 = kf + (size_t)h0 * 1025;
  const float2* kf1 = kf + (size_t)h1 * 1025;
#pragma unroll
  for (int q = 0; q < 4; ++q) {
    int k = tid + (q << 8);
    if (k == 0) {
      float2 k0 = kf0[0], k1 = kf1[0];
      float2 F0 = bufB[IDX2(0)], Fn = bufB[IDX2(1024)];
      bufA[IDX2(0)]    = make_float2(F0.x * k0.x, F0.y * k1.x);
      float2 k0n = kf0[1024], k1n = kf1[1024];
      bufA[IDX2(1024)] = make_float2(Fn.x * k0n.x, Fn.y * k1n.x);
    } else {
      float2 F = bufB[IDX2(k)], G = bufB[IDX2(2048 - k)];
      float u0r = 0.5f * (F.x + G.x), u0i = 0.5f * (F.y - G.y);   // U0[k]
      float dr_ = 0.5f * (F.x - G.x), di_ = 0.5f * (F.y + G.y);
      float u1r = di_, u1i = -dr_;                                // U1[k]
      float2 k0 = kf0[k], k1 = kf1[k];
      float z0r = u0r * k0.x - u0i * k0.y, z0i = u0r * k0.y + u0i * k0.x;
      float z1r = u1r * k1.x - u1i * k1.y, z1i = u1r * k1.y + u1i * k1.x;
      bufA[IDX2(k)]        = make_float2(z0r - z1i, z0i + z1r);
      bufA[IDX2(2048 - k)] = make_float2(z0r + z1i, z1r - z0i);
    }
  }
  __syncthreads();   // spectral writes (bufA) + reads (bufB) complete
  float2 g[8];
#pragma unroll
  for (int q = 0; q < 8; ++q) g[q] = bufA[IDX2(tid + 256 * q)];
  fft_stage0_reg_tw<1>(g, bufB, w0, tid);
  fft_mid_stages<1>(bufB, bufA, tw, tid);    // m=8: B->A, m=64: A->B
  float2 z0[4], z1[4];
  fft_final_r4_reg<1>(bufB, tid, z0, z1);
  float Dh0 = D[h0], Dh1 = D[h1];
  short* y0 = yT + (size_t)r0 * LL;
  short* y1 = y0 + LL;
  const float s = 1.0f / NFFT;
  y0[tid]       = f2bf(z0[0].x * s + Dh0 * u0[0]);
  y0[tid + 256] = f2bf(z1[0].x * s + Dh0 * u0[1]);
  y0[tid + 512] = f2bf(z0[1].x * s + Dh0 * u0[2]);
  y0[tid + 768] = f2bf(z1[1].x * s + Dh0 * u0[3]);
  y1[tid]       = f2bf(z0[0].y * s + Dh1 * u1[0]);
  y1[tid + 256] = f2bf(z1[0].y * s + Dh1 * u1[1]);
  y1[tid + 512] = f2bf(z0[1].y * s + Dh1 * u1[2]);
  y1[tid + 768] = f2bf(z1[1].y * s + Dh1 * u1[3]);
}

// ---------------------------------------------------------------------------
// Mega MLP kernel, 512 threads, 16-row tile, grid 512 -> 2 blocks/CU.
// x row-major bf16 (coalesced), yT transposed bf16. GEMM1 s=0,1 fragments
// prefetched before Phase A; GEMM2 s=0,1 prefetched before the GELU epilogue;
// setprio around MFMA clusters.
// LDS: A1[16][264]s @0 | A2[16][520]s @8448 | red @25088
//      LAST: Txn[16][260]f @0, wlds[8][258]f @16896
// ---------------------------------------------------------------------------
#define TXS 260
template <bool LAST>
__global__ __launch_bounds__(512, 4) void k_mlp(
    const short* __restrict__ W1p, const float* __restrict__ b1p,
    const short* __restrict__ W2p, const float* __restrict__ b2p,
    short* __restrict__ x, const short* __restrict__ yT,
    const float* __restrict__ ln2w, const float* __restrict__ ln2b,
    const float* __restrict__ ln1w, const float* __restrict__ ln1b,
    float* __restrict__ xnT,
    const float* __restrict__ Wout, const float* __restrict__ bout,
    float* __restrict__ out) {
  const int m0 = blockIdx.x * 16;
  const int b_ = m0 >> 10, l0 = m0 & 1023;
  const int tid = threadIdx.x;
  const int lane = tid & 63, wid = tid >> 6;       // 8 waves
  const int rg = lane >> 4, cl = lane & 15;
  __shared__ __attribute__((aligned(16))) char smem[26112];
  short* A1  = (short*)smem;                 // [16][264]
  short* A2  = (short*)(smem + 8448);        // [16][520]
  float* red = (float*)(smem + 25088);       // [8][16][2]
  float* Txn = (float*)smem;                 // [16][260] (LAST)
  float* wlds = (float*)(smem + 16896);      // [8][258]  (LAST)

  const short* w1base = W1p + (size_t)wid * 16384 + lane * 8;
  const short* w2base = W2p + (size_t)wid * 16384 + lane * 8;
  // prefetch GEMM1 s=0,1 fragments — hides L2 latency under Phase A
  bf16x8 pre[8];
#pragma unroll
  for (int n = 0; n < 8; ++n)
    pre[n] = *(const bf16x8*)(w1base + n * 512);

  // ---- Phase A: residual add (registers) + LN2 -> A1 bf16 ----
  float v[2][4];                             // [n][r], rows rg*4+r
  float wl2[2], bl2[2];
#pragma unroll
  for (int n = 0; n < 2; ++n) {
    int col = wid * 32 + n * 16 + cl;
    wl2[n] = ln2w[col]; bl2[n] = ln2b[col];
  }
  float sum[4], sq[4];
#pragma unroll
  for (int r = 0; r < 4; ++r) { sum[r] = 0.f; sq[r] = 0.f; }
#pragma unroll
  for (int n = 0; n < 2; ++n) {
    int col = wid * 32 + n * 16 + cl;
    short4v y4 = *(const short4v*)&yT[((size_t)(b_ * H + col)) * LL + l0 + rg * 4];
    float yv[4] = {b2f(y4[0]), b2f(y4[1]), b2f(y4[2]), b2f(y4[3])};
#pragma unroll
    for (int r = 0; r < 4; ++r) {
      int row = rg * 4 + r;
      float val = b2f(x[(size_t)(m0 + row) * H + col]) + yv[r];
      v[n][r] = val;
      sum[r] += val; sq[r] += val * val;
    }
  }
#pragma unroll
  for (int r = 0; r < 4; ++r) {
#pragma unroll
    for (int o = 1; o < 16; o <<= 1) {
      sum[r] += __shfl_xor(sum[r], o, 64);
      sq[r]  += __shfl_xor(sq[r], o, 64);
    }
  }
  if (cl == 0) {
#pragma unroll
    for (int r = 0; r < 4; ++r) {
      int row = rg * 4 + r;
      red[(wid * 16 + row) * 2]     = sum[r];
      red[(wid * 16 + row) * 2 + 1] = sq[r];
    }
  }
  __syncthreads();
#pragma unroll
  for (int r = 0; r < 4; ++r) {
    int row = rg * 4 + r;
    float S = 0.f, Q = 0.f;
#pragma unroll
    for (int w = 0; w < 8; ++w) { S += red[(w * 16 + row) * 2]; Q += red[(w * 16 + row) * 2 + 1]; }
    float mean = S * (1.0f / H);
    float var = Q * (1.0f / H) - mean * mean;
    float rs = rsqrtf(var + 1e-5f);
#pragma unroll
    for (int n = 0; n < 2; ++n) {
      int col = wid * 32 + n * 16 + cl;
      A1[row * 264 + col] = f2bf((v[n][r] - mean) * rs * wl2[n] + bl2[n]);
    }
  }
  __syncthreads();   // A1 complete; K-loops below are barrier-free

  // ---- Phase B: GEMM1 (16x512, K=256); wave w -> cols w*64..w*64+63 ----
  f32x4 acc1[4];
#pragma unroll
  for (int n = 0; n < 4; ++n) acc1[n] = (f32x4){0.f, 0.f, 0.f, 0.f};
  {
#pragma unroll
    for (int s = 0; s < 8; ++s) {
      const int kk = s * 32;
      bf16x8 af, bfv[4];
      if (s < 2) {
#pragma unroll
        for (int n = 0; n < 4; ++n) bfv[n] = pre[s * 4 + n];
      } else {
#pragma unroll
        for (int n = 0; n < 4; ++n)
          bfv[n] = *(const bf16x8*)(w1base + (s * 4 + n) * 512);
      }
      af = *(const bf16x8*)&A1[cl * 264 + kk + rg * 8];
      __builtin_amdgcn_s_setprio(1);
#pragma unroll
      for (int n = 0; n < 4; ++n)
        acc1[n] = __builtin_amdgcn_mfma_f32_16x16x32_bf16(af, bfv[n], acc1[n], 0, 0, 0);
      __builtin_amdgcn_s_setprio(0);
    }
  }
  // prefetch GEMM2 s=0,1 — hides W2 L2 latency under GELU epilogue + barrier
  bf16x8 pre2[4];
#pragma unroll
  for (int n = 0; n < 4; ++n)
    pre2[n] = *(const bf16x8*)(w2base + n * 512);
  // +b1, GELU -> A2 bf16
#pragma unroll
  for (int n = 0; n < 4; ++n) {
    int col = wid * 64 + n * 16 + cl;
    float bb = b1p[col];
#pragma unroll
    for (int r = 0; r < 4; ++r) {
      int row = rg * 4 + r;
      float g = acc1[n][r] + bb;
      g = 0.5f * g * (1.0f + erff(g * 0.70710678118654752f));
      A2[row * 520 + col] = f2bf(g);
    }
  }
  __syncthreads();   // A2 complete

  // ---- Phase C: GEMM2 (16x256, K=512); wave w -> cols w*32..w*32+31 ----
  f32x4 acc2[2];
#pragma unroll
  for (int n = 0; n < 2; ++n) acc2[n] = (f32x4){0.f, 0.f, 0.f, 0.f};
  {
#pragma unroll
    for (int s = 0; s < 16; ++s) {
      const int kk = s * 32;
      bf16x8 af, bfv[2];
      if (s < 2) {
#pragma unroll
        for (int n = 0; n < 2; ++n) bfv[n] = pre2[s * 2 + n];
      } else {
#pragma unroll
        for (int n = 0; n < 2; ++n)
          bfv[n] = *(const bf16x8*)(w2base + (s * 2 + n) * 512);
      }
      af = *(const bf16x8*)&A2[cl * 520 + kk + rg * 8];
      __builtin_amdgcn_s_setprio(1);
#pragma unroll
      for (int n = 0; n < 2; ++n)
        acc2[n] = __builtin_amdgcn_mfma_f32_16x16x32_bf16(af, bfv[n], acc2[n], 0, 0, 0);
      __builtin_amdgcn_s_setprio(0);
    }
  }

  // ---- Phase D: vf = acc2 + b2 + v; LN1-next + xnT | output proj ----
  float bv[2], wl1[2], bl1[2];
#pragma unroll
  for (int n = 0; n < 2; ++n) {
    int col = wid * 32 + n * 16 + cl;
    bv[n] = b2p[col];
    if (!LAST) { wl1[n] = ln1w[col]; bl1[n] = ln1b[col]; }
  }
#pragma unroll
  for (int r = 0; r < 4; ++r) { sum[r] = 0.f; sq[r] = 0.f; }
#pragma unroll
  for (int n = 0; n < 2; ++n) {
#pragma unroll
    for (int r = 0; r < 4; ++r) {
      float vf = acc2[n][r] + bv[n] + v[n][r];
      acc2[n][r] = vf;
      sum[r] += vf; sq[r] += vf * vf;
    }
  }

  if (LAST) {
    __syncthreads();   // all waves done reading A2 before Txn overlays it
#pragma unroll
    for (int n = 0; n < 2; ++n) {
      int col = wid * 32 + n * 16 + cl;
#pragma unroll
      for (int r = 0; r < 4; ++r) {
        int row = rg * 4 + r;
        Txn[row * TXS + col] = acc2[n][r];
      }
    }
#pragma unroll
    for (int it = 0; it < 4; ++it) {
      int idx = tid + (it << 9);
      wlds[(idx >> 8) * 258 + (idx & 255)] = Wout[idx];
    }
    __syncthreads();
    if (tid < 128) {
      int row = tid >> 3, co = tid & 7;
      float p = bout[co];
      const float* tr = Txn + row * TXS;
      const float* wr = wlds + co * 258;
#pragma unroll 4
      for (int c = 0; c < H; ++c) p += tr[c] * wr[c];
      out[((b_ * COUT + co) << 10) + l0 + row] = p;
    }
  } else {
#pragma unroll
    for (int r = 0; r < 4; ++r) {
#pragma unroll
      for (int o = 1; o < 16; o <<= 1) {
        sum[r] += __shfl_xor(sum[r], o, 64);
        sq[r]  += __shfl_xor(sq[r], o, 64);
      }
    }
    if (cl == 0) {
#pragma unroll
      for (int r = 0; r < 4; ++r) {
        int row = rg * 4 + r;
        red[(wid * 16 + row) * 2]     = sum[r];
        red[(wid * 16 + row) * 2 + 1] = sq[r];
      }
    }
    __syncthreads();   // red ready AND all waves done with A1/A2 (Txn safe)
#pragma unroll
    for (int r = 0; r < 4; ++r) {
      int row = rg * 4 + r;
      float S = 0.f, Q = 0.f;
#pragma unroll
      for (int w = 0; w < 8; ++w) { S += red[(w * 16 + row) * 2]; Q += red[(w * 16 + row) * 2 + 1]; }
      float mean = S * (1.0f / H);
      float var = Q * (1.0f / H) - mean * mean;
      float rs = rsqrtf(var + 1e-5f);
#pragma unroll
      for (int n = 0; n < 2; ++n) {
        int col = wid * 32 + n * 16 + cl;
        float vf = acc2[n][r];
        x[(size_t)(m0 + row) * H + col] = f2bf(vf);
        Txn[row * TXS + col] = (vf - mean) * rs * wl1[n] + bl1[n];
      }
    }
    __syncthreads();
    // transposed copy: 512 threads, each moves 8 l-contiguous floats
    int h = tid & 255, seg = (tid >> 8) * 8;
    float tmp[8];
#pragma unroll
    for (int l = 0; l < 8; ++l) tmp[l] = Txn[(seg + l) * TXS + h];
    float* dst = xnT + ((size_t)(b_ * H + h)) * LL + l0 + seg;
#pragma unroll
    for (int l = 0; l < 8; l += 4) {
      float4 v4 = {tmp[l], tmp[l + 1], tmp[l + 2], tmp[l + 3]};
      *(float4*)&dst[l] = v4;
    }
  }
}

extern "C" void kernel_launch(void* const* d_in, const int* in_sizes, int n_in,
                              void* d_out, int out_size, void* d_ws, size_t ws_size,
                              hipStream_t stream) {
  const float* stim  = (const float*)d_in[0];
  const float* init  = (const float*)d_in[1];
  const float* A_re  = (const float*)d_in[2];
  const float* A_im  = (const float*)d_in[3];
  const float* C_re  = (const float*)d_in[4];
  const float* C_im  = (const float*)d_in[5];
  const float* Dp    = (const float*)d_in[6];
  const float* lstep = (const float*)d_in[7];
  const float* ln1w  = (const float*)d_in[8];
  const float* ln1b  = (const float*)d_in[9];
  const float* ln2w  = (const float*)d_in[10];
  const float* ln2b  = (const float*)d_in[11];
  const float* W1    = (const float*)d_in[12];
  const float* b1    = (const float*)d_in[13];
  const float* W2    = (const float*)d_in[14];
  const float* b2    = (const float*)d_in[15];
  const float* Win   = (const float*)d_in[16];
  const float* bin   = (const float*)d_in[17];
  const float* Wst   = (const float*)d_in[18];
  const float* bst   = (const float*)d_in[19];
  const float* Wout  = (const float*)d_in[20];
  const float* bout  = (const float*)d_in[21];
  float* out = (float*)d_out;
  float* ws = (float*)d_ws;

  size_t o = 0;
  auto alloc = [&](size_t nfloats) { size_t r = o; o += (nfloats + 63) & ~(size_t)63; return r; };
  short*  x    = (short*)(ws + alloc((size_t)BB * LL * H / 2));
  float*  xnT  = ws + alloc((size_t)BB * H * LL);
  short*  yT   = (short*)(ws + alloc((size_t)BB * H * LL / 2));
  float2* kf   = (float2*)(ws + alloc((size_t)NL * H * 1025 * 2));
  short*  W1s  = (short*)(ws + alloc((size_t)NL * 512 * 256 / 2));
  short*  W2s  = (short*)(ws + alloc((size_t)NL * 256 * 512 / 2));
  float*  WinT = ws + alloc((size_t)64 * 256);
  float*  sp   = ws + alloc((size_t)BB * H);
  float2* tw   = (float2*)(ws + alloc((size_t)2048 * 2));
  (void)ws_size; (void)in_sizes; (void)n_in; (void)out_size;

  k_setup<<<512, 256, 0, stream>>>(W1, W2, Win, init, Wst, bst, bin,
                                   W1s, W2s, WinT, sp, tw);
  k_kernelfft<<<NL * H, 256, 0, stream>>>(A_re, A_im, C_re, C_im, lstep, tw, kf);
  k_in_ln1<<<BB * 64, 256, 0, stream>>>(stim, WinT, sp, ln1w, ln1b, x, xnT);

  for (int i = 0; i < NL; ++i) {
    k_conv<<<BB * H / 2, 256, 0, stream>>>(xnT, kf + (size_t)i * H * 1025,
                                           Dp + i * H, tw, yT);
    if (i < NL - 1) {
      k_mlp<false><<<512, 512, 0, stream>>>(
          W1s + (size_t)i * 512 * 256, b1 + i * 512,
          W2s + (size_t)i * 256 * 512, b2 + i * H,
          x, yT, ln2w + i * H, ln2b + i * H,
          ln1w + (i + 1) * H, ln1b + (i + 1) * H, xnT,
          nullptr, nullptr, nullptr);
    } else {
      k_mlp<true><<<512, 512, 0, stream>>>(
          W1s + (size_t)i * 512 * 256, b1 + i * 512,
          W2s + (size_t)i * 256 * 512, b2 + i * H,
          x, yT, ln2w + i * H, ln2b + i * H,
          nullptr, nullptr, nullptr,
          Wout, bout, out);
    }
  }
}